// Round 5
// baseline (195.618 us; speedup 1.0000x reference)
//
#include <hip/hip_runtime.h>
#include <math.h>

// Problem constants
#define NB 4      // batch
#define C  128    // channels (q/k/v/out)
#define CCH 256   // context channels
#define HH 64
#define WW 64
#define NN 4096   // HH*WW
#define NS 1024   // source-resolution pixel count (32*32)
#define HC 32
#define WC 32
#define PP 66     // padded spatial dim for conv input (64 + 2 halo)
#define LOG2E 1.44269504088896f
#define NSPLIT 8  // flash split-K factor (8 fine rows / 4 source rows each)

typedef unsigned short u16;
typedef unsigned int uint32;
typedef short s16x8 __attribute__((ext_vector_type(8)));    // 8 bf16 = MFMA A/B frag
typedef float f32x4 __attribute__((ext_vector_type(4)));    // 16x16 MFMA C/D frag
typedef float f32x16 __attribute__((ext_vector_type(16)));  // 32x32 MFMA C/D frag

#if __has_builtin(__builtin_amdgcn_exp2f)
#define EXP2(x) __builtin_amdgcn_exp2f(x)
#else
#define EXP2(x) __expf((x) * 0.69314718056f)
#endif

__device__ __forceinline__ u16 f2bf(float f) {
    uint32 u = __float_as_uint(f);
    u += 0x7fffu + ((u >> 16) & 1u);
    return (u16)(u >> 16);
}
__device__ __forceinline__ float bf2f(u16 h) {
    return __uint_as_float((uint32)h << 16);
}

// ---------------------------------------------------------------------------
// 1) prep2: [0,256) ctx transpose-cast (source res) -> ctx_s bf16 [b][1024][cc]
//    [256,768) sr transpose-cast -> sr_t bf16 [b][4096][C]
//    [768,1664) weight prep   [1664,2753) zero att_t
// ---------------------------------------------------------------------------
__global__ __launch_bounds__(256) void prep2(const float* __restrict__ ctx,
                                             const float* __restrict__ sr,
                                             const float* __restrict__ Wq,
                                             const float* __restrict__ Wk,
                                             const float* __restrict__ Wv,
                                             const float* __restrict__ Wp,
                                             u16* __restrict__ ctx_s,
                                             u16* __restrict__ sr_t,
                                             u16* __restrict__ wbf,
                                             u16* __restrict__ wt,
                                             uint4* __restrict__ att_z) {
    __shared__ float ls[64 * 65];
    int blk = blockIdx.x;
    int tid = threadIdx.x;

    if (blk < 256) {
        // ctx f32 [b][cc][1024] -> ctx_s bf16 [b][1024][cc], 64x64 tiles
        int idx = blk;
        int n0 = (idx & 15) * 64;
        int ci0 = ((idx >> 4) & 3) * 64;
        int b = idx >> 6;
        const float* inb = ctx + ((size_t)b * CCH + ci0) * NS + n0;
#pragma unroll
        for (int L = 0; L < 4; L++) {
            int fc = tid + L * 256;
            int nc = fc & 15, ci = fc >> 4;
            float4 v = *(const float4*)(inb + (size_t)ci * NS + nc * 4);
            float* d = &ls[ci * 65 + nc * 4];
            d[0] = v.x; d[1] = v.y; d[2] = v.z; d[3] = v.w;
        }
        __syncthreads();
        u16* ob = ctx_s + ((size_t)b * NS + n0) * CCH + ci0;
#pragma unroll
        for (int j = 0; j < 16; j++) {
            int o = tid + j * 256;
            int ci = o & 63, n = o >> 6;
            ob[(size_t)n * CCH + ci] = f2bf(ls[ci * 65 + n]);
        }
    } else if (blk < 768) {
        // sr f32 [b][C][4096] -> sr_t bf16 [b][4096][C]
        int idx = blk - 256;
        int n0 = (idx & 63) * 64;
        int ci0 = ((idx >> 6) & 1) * 64;
        int b = idx >> 7;
        const float* inb = sr + ((size_t)b * C + ci0) * NN + n0;
#pragma unroll
        for (int L = 0; L < 4; L++) {
            int fc = tid + L * 256;
            int nc = fc & 15, ci = fc >> 4;
            float4 v = *(const float4*)(inb + (size_t)ci * NN + nc * 4);
            float* d = &ls[ci * 65 + nc * 4];
            d[0] = v.x; d[1] = v.y; d[2] = v.z; d[3] = v.w;
        }
        __syncthreads();
        u16* ob = sr_t + ((size_t)b * NN + n0) * C + ci0;
#pragma unroll
        for (int j = 0; j < 16; j++) {
            int o = tid + j * 256;
            int ci = o & 63, n = o >> 6;
            ob[(size_t)n * C + ci] = f2bf(ls[ci * 65 + n]);
        }
    } else if (blk < 1664) {
        int i = (blk - 768) * 256 + tid;   // 0..229375
        if (i < 81920) {
            float v;
            if (i < 16384) v = Wq[i] * LOG2E;
            else if (i < 49152) v = Wk[i - 16384];
            else v = Wv[i - 49152];
            wbf[i] = f2bf(v);
        } else {
            int idx = i - 81920;
            int ciin = idx & 31;
            int co = (idx >> 5) & 127;
            int cb = (idx >> 12) & 3;
            int pos = idx >> 14;
            int ky = pos / 3, kx = pos - ky * 3;
            int ci = cb * 32 + ciin;
            wt[idx] = f2bf(Wp[((size_t)(co * C + ci) * 3 + ky) * 3 + kx]);
        }
    } else {
        int i = (blk - 1664) * 256 + tid;   // 0..278783
        if (i < 278784) att_z[i] = make_uint4(0, 0, 0, 0);
    }
}

// ---------------------------------------------------------------------------
// 2) proj_all2: x<32 -> q projection (N=4096, Cin=128, sr_t);
//               x>=32 -> K AND V from one staged ctx_s tile (N=1024, Cin=256).
// ---------------------------------------------------------------------------
__global__ __launch_bounds__(256) void proj_all2(const u16* __restrict__ sr_t,
                                                 const u16* __restrict__ ctx_s,
                                                 const u16* __restrict__ wbf,
                                                 const float* __restrict__ bq,
                                                 const float* __restrict__ bk,
                                                 const float* __restrict__ bv,
                                                 u16* __restrict__ q_t,
                                                 u16* __restrict__ k_s,
                                                 u16* __restrict__ v_s) {
    __shared__ u16 xs[128 * 64];      // 16 KB (kv uses first 8 KB)
    __shared__ u16 wsm[2][128 * 64];  // 32 KB
    int b = blockIdx.y;
    int tid = threadIdx.x;
    int w = tid >> 6, lane = tid & 63, l31 = lane & 31, half = lane >> 5;
    int xh = w >> 1, wh = w & 1;

    if (blockIdx.x < 32) {
        // ---- Q: 128 n x 128 co, Cin=128 ----
        int n0 = blockIdx.x * 128;
        const u16* xb = sr_t + (size_t)b * NN * C;
        f32x16 acc[2][2];
#pragma unroll
        for (int xt = 0; xt < 2; xt++)
#pragma unroll
            for (int wt2 = 0; wt2 < 2; wt2++)
#pragma unroll
                for (int i = 0; i < 16; i++) acc[xt][wt2][i] = 0.f;
        for (int c0i = 0; c0i < 2; c0i++) {
            int c0 = c0i * 64;
            __syncthreads();
#pragma unroll
            for (int t = 0; t < 4; t++) {
                int CI = t * 256 + tid;
                int row = CI >> 3, sl = CI & 7;
                int lc = sl ^ (row & 7);
                __builtin_amdgcn_global_load_lds(
                    (const __attribute__((address_space(1))) void*)(xb + (size_t)(n0 + row) * C + c0 + lc * 8),
                    (__attribute__((address_space(3))) void*)&xs[(size_t)CI * 8], 16, 0, 0);
            }
#pragma unroll
            for (int t = 0; t < 4; t++) {
                int CI = t * 256 + tid;
                int co = CI >> 3, sl = CI & 7;
                int lc = sl ^ (co & 7);
                __builtin_amdgcn_global_load_lds(
                    (const __attribute__((address_space(1))) void*)(wbf + (size_t)co * C + c0 + lc * 8),
                    (__attribute__((address_space(3))) void*)&wsm[0][(size_t)CI * 8], 16, 0, 0);
            }
            __syncthreads();
#pragma unroll
            for (int kg = 0; kg < 4; kg++) {
                int pc = ((kg * 2 + half) ^ (l31 & 7)) * 8;
                s16x8 xf[2], wf2[2];
#pragma unroll
                for (int xt = 0; xt < 2; xt++)
                    xf[xt] = *(const s16x8*)&xs[(xh * 64 + xt * 32 + l31) * 64 + pc];
#pragma unroll
                for (int wt2 = 0; wt2 < 2; wt2++)
                    wf2[wt2] = *(const s16x8*)&wsm[0][(wh * 64 + wt2 * 32 + l31) * 64 + pc];
#pragma unroll
                for (int xt = 0; xt < 2; xt++)
#pragma unroll
                    for (int wt2 = 0; wt2 < 2; wt2++)
                        acc[xt][wt2] = __builtin_amdgcn_mfma_f32_32x32x16_bf16(xf[xt], wf2[wt2], acc[xt][wt2], 0, 0, 0);
            }
        }
        u16* ot = q_t + (size_t)b * NN * C;
        float bv2[2];
#pragma unroll
        for (int wt2 = 0; wt2 < 2; wt2++) bv2[wt2] = bq[wh * 64 + wt2 * 32 + l31] * LOG2E;
#pragma unroll
        for (int xt = 0; xt < 2; xt++)
#pragma unroll
            for (int r = 0; r < 16; r++) {
                int n = n0 + xh * 64 + xt * 32 + (r & 3) + 8 * (r >> 2) + 4 * half;
#pragma unroll
                for (int wt2 = 0; wt2 < 2; wt2++)
                    ot[(size_t)n * C + wh * 64 + wt2 * 32 + l31] = f2bf(acc[xt][wt2][r] + bv2[wt2]);
            }
    } else {
        // ---- K & V: 64 source px x 128 co, Cin=256, ctx staged once ----
        int n0 = (blockIdx.x - 32) * 64;
        const u16* xb = ctx_s + (size_t)b * NS * CCH;
        const u16* wkb = wbf + 16384;
        const u16* wvb = wbf + 49152;
        f32x16 acck[2], accv[2];   // [wt2]; wave: n-tile xh*32, co wh*64+wt2*32
#pragma unroll
        for (int wt2 = 0; wt2 < 2; wt2++)
#pragma unroll
            for (int i = 0; i < 16; i++) { acck[wt2][i] = 0.f; accv[wt2][i] = 0.f; }
        for (int c0i = 0; c0i < 4; c0i++) {
            int c0 = c0i * 64;
            __syncthreads();
#pragma unroll
            for (int t = 0; t < 2; t++) {          // 64 rows x 8 chunks
                int CI = t * 256 + tid;
                int row = CI >> 3, sl = CI & 7;
                int lc = sl ^ (row & 7);
                __builtin_amdgcn_global_load_lds(
                    (const __attribute__((address_space(1))) void*)(xb + (size_t)(n0 + row) * CCH + c0 + lc * 8),
                    (__attribute__((address_space(3))) void*)&xs[(size_t)CI * 8], 16, 0, 0);
            }
#pragma unroll
            for (int t = 0; t < 4; t++) {
                int CI = t * 256 + tid;
                int co = CI >> 3, sl = CI & 7;
                int lc = sl ^ (co & 7);
                __builtin_amdgcn_global_load_lds(
                    (const __attribute__((address_space(1))) void*)(wkb + (size_t)co * CCH + c0 + lc * 8),
                    (__attribute__((address_space(3))) void*)&wsm[0][(size_t)CI * 8], 16, 0, 0);
            }
#pragma unroll
            for (int t = 0; t < 4; t++) {
                int CI = t * 256 + tid;
                int co = CI >> 3, sl = CI & 7;
                int lc = sl ^ (co & 7);
                __builtin_amdgcn_global_load_lds(
                    (const __attribute__((address_space(1))) void*)(wvb + (size_t)co * CCH + c0 + lc * 8),
                    (__attribute__((address_space(3))) void*)&wsm[1][(size_t)CI * 8], 16, 0, 0);
            }
            __syncthreads();
#pragma unroll
            for (int kg = 0; kg < 4; kg++) {
                int pc = ((kg * 2 + half) ^ (l31 & 7)) * 8;
                s16x8 xf = *(const s16x8*)&xs[(xh * 32 + l31) * 64 + pc];
                s16x8 wfk[2], wfv[2];
#pragma unroll
                for (int wt2 = 0; wt2 < 2; wt2++) {
                    wfk[wt2] = *(const s16x8*)&wsm[0][(wh * 64 + wt2 * 32 + l31) * 64 + pc];
                    wfv[wt2] = *(const s16x8*)&wsm[1][(wh * 64 + wt2 * 32 + l31) * 64 + pc];
                }
#pragma unroll
                for (int wt2 = 0; wt2 < 2; wt2++) {
                    acck[wt2] = __builtin_amdgcn_mfma_f32_32x32x16_bf16(xf, wfk[wt2], acck[wt2], 0, 0, 0);
                    accv[wt2] = __builtin_amdgcn_mfma_f32_32x32x16_bf16(wfv[wt2], xf, accv[wt2], 0, 0, 0);
                }
            }
        }
        // K epilogue: T-layout k_s[b][n][co]
        u16* ok = k_s + (size_t)b * NS * C;
#pragma unroll
        for (int wt2 = 0; wt2 < 2; wt2++) {
            float bvk = bk[wh * 64 + wt2 * 32 + l31];
#pragma unroll
            for (int r = 0; r < 16; r++) {
                int n = n0 + xh * 32 + (r & 3) + 8 * (r >> 2) + 4 * half;
                ok[(size_t)n * C + wh * 64 + wt2 * 32 + l31] = f2bf(acck[wt2][r] + bvk);
            }
        }
        // V epilogue: N-layout v_s[b][co][n]
        u16* ov = v_s + (size_t)b * C * NS;
#pragma unroll
        for (int wt2 = 0; wt2 < 2; wt2++)
#pragma unroll
            for (int r = 0; r < 16; r++) {
                int co = wh * 64 + wt2 * 32 + (r & 3) + 8 * (r >> 2) + 4 * half;
                ov[(size_t)co * NS + n0 + xh * 32 + l31] = f2bf(accv[wt2][r] + bv[co]);
            }
    }
}

// ---------------------------------------------------------------------------
// 3) upsample_v: v_s [b][C][1024] -> v [b][C][4096]
//    (bilinear, half-pixel centers, clamped — commutes with 1x1 conv)
// ---------------------------------------------------------------------------
__global__ __launch_bounds__(256) void upsample_v(const u16* __restrict__ v_s,
                                                  u16* __restrict__ v_bf) {
    __shared__ u16 lsv[NS];
    int idx = blockIdx.x;
    int tid = threadIdx.x;
    // one (b,c) plane: 1024 -> 4096
    int c = idx & 127, b = idx >> 7;
    const u16* vp = v_s + ((size_t)b * C + c) * NS;
    if (tid < 128) *(uint4*)&lsv[tid * 8] = *(const uint4*)(vp + tid * 8);
    __syncthreads();
    u16* ob = v_bf + ((size_t)b * C + c) * NN;
#pragma unroll
    for (int j = 0; j < 16; j++) {
        int n = tid + j * 256;
        int y = n >> 6, x = n & 63;
        float sy = y * 0.5f - 0.25f;
        float sx = x * 0.5f - 0.25f;
        int y0 = (int)floorf(sy), x0 = (int)floorf(sx);
        float wy = sy - (float)y0, wx = sx - (float)x0;
        int y0c = y0 < 0 ? 0 : y0;
        int y1c = (y0 + 1 > HC - 1) ? HC - 1 : y0 + 1;
        int x0c = x0 < 0 ? 0 : x0;
        int x1c = (x0 + 1 > WC - 1) ? WC - 1 : x0 + 1;
        float v00 = bf2f(lsv[y0c * WC + x0c]), v01 = bf2f(lsv[y0c * WC + x1c]);
        float v10 = bf2f(lsv[y1c * WC + x0c]), v11 = bf2f(lsv[y1c * WC + x1c]);
        ob[n] = f2bf((1.f - wy) * ((1.f - wx) * v00 + wx * v01)
                   +        wy  * ((1.f - wx) * v10 + wx * v11));
    }
}

// ---------------------------------------------------------------------------
// 4) Flash attention v16: v11 schedule (sC lookahead: score tile computed at
//    even it, consumed at odd it — keeps the 8-MFMA chain OFF the critical
//    path; v15's removal of it cost 18us), 2-buffer ksr (stage odd it ->
//    read next even it, verified 1-barrier gap), LDS 48 KB, and NSPLIT=8:
//    grid 1024 blocks -> 3 blocks/CU (LDS-limited), 12 waves/CU vs 8.
//    v15 lesson: occupancy is grid-capped at 512 blocks; LDS cuts alone
//    do nothing.
// ---------------------------------------------------------------------------
__global__ __launch_bounds__(256, 3) void flash_mfma(const u16* __restrict__ qt_p,
                                                     const u16* __restrict__ ks_p,
                                                     const u16* __restrict__ vt_p,
                                                     u16* __restrict__ part,
                                                     float* __restrict__ lpart) {
    __shared__ u16 ksr[2][32 * 128];   // 2 x 8 KB rotating source-K row buffers
    __shared__ u16 vs[2][128 * 64];    // 2 x 16 KB fine-V double buffer

    int ib = blockIdx.x;
    int split = ib & 7;                // consecutive ib -> different XCD & split
    int b = (ib >> 3) & 3;
    int qtile = ib >> 5;
    int n0 = qtile * 128;
    int tid = threadIdx.x;
    int w = tid >> 6, lane = tid & 63, l31 = lane & 31, half = lane >> 5;

    const u16* qtb = qt_p + (size_t)b * NN * C;
    const u16* ksb = ks_p + (size_t)b * NS * C;
    const u16* vtb = vt_p + (size_t)b * C * NN;

    // stage source-K row r (32 px x 128 ch = 8 KB) into ksr[buf]
    auto stageKrow = [&](int buf, int r) {
#pragma unroll
        for (int t = 0; t < 2; t++) {
            int CI = t * 256 + tid;            // chunk 0..511
            int row = CI >> 4;                 // src px within row (jx)
            int lc = (CI & 15) ^ (row & 15);
            __builtin_amdgcn_global_load_lds(
                (const __attribute__((address_space(1))) void*)(ksb + (size_t)(r * 32 + row) * C + lc * 8),
                (__attribute__((address_space(3))) void*)&ksr[buf][(size_t)CI * 8], 16, 0, 0);
        }
    };
    auto stageV = [&](int buf, int m0) {
#pragma unroll
        for (int t = 0; t < 4; t++) {
            int CI = (w * 4 + t) * 64 + lane;
            int c = CI >> 3;
            int lc = (CI & 7) ^ (c & 7);
            __builtin_amdgcn_global_load_lds(
                (const __attribute__((address_space(1))) void*)(vtb + (size_t)c * NN + m0 + lc * 8),
                (__attribute__((address_space(3))) void*)&vs[buf][(w * 4 + t) * 512], 16, 0, 0);
        }
    };

    int qrow = n0 + w * 32 + l31;
    s16x8 qf[8];
#pragma unroll
    for (int kg = 0; kg < 8; kg++)
        qf[kg] = *(const s16x8*)(qtb + (size_t)qrow * C + kg * 16 + half * 8);

    // score tile: rows = 32 src px of one source row, cols = 32 q
    auto scoreTile = [&](int buf) {
        f32x16 st;
#pragma unroll
        for (int i = 0; i < 16; i++) st[i] = 0.f;
        const u16* kb = &ksr[buf][0];
#pragma unroll
        for (int kg = 0; kg < 8; kg++) {
            int pc = ((kg * 2 + half) ^ (l31 & 15)) * 8;
            s16x8 kf = *(const s16x8*)&kb[l31 * 128 + pc];
            st = __builtin_amdgcn_mfma_f32_32x32x16_bf16(kf, qf[kg], st, 0, 0, 0);
        }
        return st;
    };

    int m_base = split * 512;
    int j0 = split * 4;   // first source row of this split's window

    // prologue: sA=row(j0-1 clamp), sB=row(j0); then buf0 <- row(j0+1) for it0
    stageKrow(0, split == 0 ? 0 : j0 - 1);
    stageKrow(1, j0);
    stageV(0, m_base);
    __syncthreads();
    f32x16 sA = scoreTile(0);
    f32x16 sB = scoreTile(1);
    __syncthreads();                   // all waves done reading buf0
    stageKrow(0, j0 + 1);              // j0+1 <= 29 always
    __syncthreads();

    f32x16 sC;                          // lookahead tile (computed at even it)
    f32x16 oacc[4];
#pragma unroll
    for (int mt = 0; mt < 4; mt++)
#pragma unroll
        for (int i = 0; i < 16; i++) oacc[mt][i] = 0.f;
    float lsum = 0.f;

#pragma unroll 2
    for (int it = 0; it < 8; it++) {    // y = 8*split + it
        int buf = it & 1;
        int m0 = m_base + it * 64;
        if (it < 7) stageV(buf ^ 1, m0 + 64);
        if ((it & 1) == 0) {
            // EVEN (u=it/2): rows (j0+u-1, j0+u); lookahead tile row j0+1+u
            int rn = j0 + 1 + (it >> 1);
            if (rn <= 31) sC = scoreTile((it >> 1) & 1);
        } else {
            // ODD: stage row j0+2+u into the other buffer; advance window
            int u = it >> 1;
            int rs = j0 + 2 + u;
            if (rs <= 31) stageKrow((u + 1) & 1, rs);
            sA = sB;
            int rn = j0 + 1 + u;
            if (rn <= 31) sB = sC;      // else clamp: keep row 31
        }

        // y-lerp: even y -> (0.25,0.75), odd y -> (0.75,0.25) on (rlo,rhi)
        float wB = (it & 1) ? 0.25f : 0.75f;
        float wA = 1.0f - wB;
        float cc[16];
#pragma unroll
        for (int i = 0; i < 16; i++) cc[i] = wA * sA[i] + wB * sB[i];

        // boundary exchange across lane-halves (rows interleave in blocks of 4)
        float xr0  = __shfl_xor(cc[0], 32);
        float xr3  = __shfl_xor(cc[3], 32);
        float xr4  = __shfl_xor(cc[4], 32);
        float xr7  = __shfl_xor(cc[7], 32);
        float xr8  = __shfl_xor(cc[8], 32);
        float xr11 = __shfl_xor(cc[11], 32);
        float xr12 = __shfl_xor(cc[12], 32);
        float xr15 = __shfl_xor(cc[15], 32);
        float d0s[4], d5s[4];
        d0s[0] = half ? xr3  : cc[0];   // x-block edge rows (clamped at 0)
        d0s[1] = half ? xr7  : xr3;
        d0s[2] = half ? xr11 : xr7;
        d0s[3] = half ? xr15 : xr11;
        d5s[0] = half ? xr4  : xr0;     // (clamped at 31)
        d5s[1] = half ? xr8  : xr4;
        d5s[2] = half ? xr12 : xr8;
        d5s[3] = half ? cc[15] : xr12;

        const u16* vsb = &vs[buf][0];
#pragma unroll
        for (int s = 0; s < 4; s++) {   // x-block xb = 2*s + half; x = 8*xb..+7
            float d0 = d0s[s], d1 = cc[4 * s], d2 = cc[4 * s + 1];
            float d3 = cc[4 * s + 2], d4 = cc[4 * s + 3], d5 = d5s[s];
            float e1 = 0.75f * d1, e2 = 0.75f * d2, e3 = 0.75f * d3, e4 = 0.75f * d4;
            float p0 = EXP2(fmaf(0.25f, d0, e1));
            float p1 = EXP2(fmaf(0.25f, d2, e1));
            float p2 = EXP2(fmaf(0.25f, d1, e2));
            float p3 = EXP2(fmaf(0.25f, d3, e2));
            float p4 = EXP2(fmaf(0.25f, d2, e3));
            float p5 = EXP2(fmaf(0.25f, d4, e3));
            float p6 = EXP2(fmaf(0.25f, d3, e4));
            float p7 = EXP2(fmaf(0.25f, d5, e4));
            lsum += ((p0 + p1) + (p2 + p3)) + ((p4 + p5) + (p6 + p7));
            union { uint32 u[4]; s16x8 v; } pu;
            pu.u[0] = __builtin_amdgcn_perm(__float_as_uint(p1), __float_as_uint(p0), 0x07060302u);
            pu.u[1] = __builtin_amdgcn_perm(__float_as_uint(p3), __float_as_uint(p2), 0x07060302u);
            pu.u[2] = __builtin_amdgcn_perm(__float_as_uint(p5), __float_as_uint(p4), 0x07060302u);
            pu.u[3] = __builtin_amdgcn_perm(__float_as_uint(p7), __float_as_uint(p6), 0x07060302u);
            int pcv = ((s * 2 + half) ^ (l31 & 7)) * 8;
#pragma unroll
            for (int mt = 0; mt < 4; mt++) {
                s16x8 vf = *(const s16x8*)&vsb[(mt * 32 + l31) * 64 + pcv];
                oacc[mt] = __builtin_amdgcn_mfma_f32_32x32x16_bf16(vf, pu.v, oacc[mt], 0, 0, 0);
            }
        }
        __syncthreads();
    }

    float lt = lsum + __shfl_xor(lsum, 32);
    if (half == 0) lpart[(size_t)split * NB * NN + (size_t)b * NN + qrow] = lt;
    u16* pb = part + ((size_t)split * NB + b) * (size_t)C * NN;
#pragma unroll
    for (int mt = 0; mt < 4; mt++)
#pragma unroll
        for (int r = 0; r < 16; r++) {
            int c = mt * 32 + (r & 3) + 8 * (r >> 2) + 4 * half;
            pb[(size_t)c * NN + n0 + w * 32 + l31] = f2bf(oacc[mt][r]);
        }
}

// ---------------------------------------------------------------------------
// 5) Combine (NSPLIT=8 via macro).
// ---------------------------------------------------------------------------
__global__ __launch_bounds__(256) void flash_combine(const u16* __restrict__ part,
                                                     const float* __restrict__ lpart,
                                                     u16* __restrict__ att_t) {
    __shared__ u16 ts[128 * 66];
    __shared__ float linv[64];
    int b = blockIdx.y;
    int nt = blockIdx.x;
    int n0 = nt * 64;
    int tid = threadIdx.x;
    if (tid < 64) {
        float s = 0.f;
#pragma unroll
        for (int sp = 0; sp < NSPLIT; sp++)
            s += lpart[(size_t)sp * NB * NN + (size_t)b * NN + n0 + tid];
        linv[tid] = 1.0f / s;
    }
    __syncthreads();
#pragma unroll
    for (int j = 0; j < 32; j++) {
        int e = tid + j * 256;
        int n = e & 63, c = e >> 6;
        float o = 0.f;
#pragma unroll
        for (int sp = 0; sp < NSPLIT; sp++)
            o += bf2f(part[((size_t)sp * NB + b) * (size_t)C * NN + (size_t)c * NN + n0 + n]);
        ts[c * 66 + n] = f2bf(o * linv[n]);
    }
    __syncthreads();
    u16* ob = att_t + ((size_t)b * PP * PP + (size_t)(nt + 1) * PP + 1) * C;
#pragma unroll
    for (int j = 0; j < 32; j++) {
        int o = tid + j * 256;
        int c = o & 127, n = o >> 7;
        ob[(size_t)n * C + c] = ts[c * 66 + n];
    }
}

// ---------------------------------------------------------------------------
// 6) Conv3x3 MFMA + residual (unchanged).
// ---------------------------------------------------------------------------
__global__ __launch_bounds__(256) void conv3x3_mfma(const u16* __restrict__ att_t,
                                                    const u16* __restrict__ wt,
                                                    const float* __restrict__ bp,
                                                    const float* __restrict__ sr,
                                                    const float* __restrict__ gamma,
                                                    float* __restrict__ out) {
    __shared__ u16 in_s[2][4 * 102 * 8];
    int ib = blockIdx.x;
    int b = (ib & 7) >> 1;
    int rr = ((ib >> 3) << 1) | (ib & 1);
    int y = rr >> 1;
    int x0 = (rr & 1) * 32;
    int tid = threadIdx.x;
    int w = tid >> 6, lane = tid & 63, l = tid & 15, quad = (tid >> 4) & 3;
    const u16* ab = att_t + (size_t)b * (PP * PP * C);

    auto stage = [&](int cib, int bufi) {
        u16* base = &in_s[bufi][w * 102 * 8];
        const u16* gsrc = ab + cib * 32 + w * 8;
#pragma unroll
        for (int t = 0; t < 2; t++) {
            int idx = t * 64 + lane;
            int r = idx / 34, xp = idx - r * 34;
            if (t == 0 || lane < 38)
                __builtin_amdgcn_global_load_lds(
                    (const __attribute__((address_space(1))) void*)(gsrc + (size_t)((y + r) * PP + x0 + xp) * C),
                    (__attribute__((address_space(3))) void*)(base + (size_t)t * 64 * 8), 16, 0, 0);
        }
    };

    f32x4 accr[2][2];
#pragma unroll
    for (int cf = 0; cf < 2; cf++)
#pragma unroll
        for (int nf = 0; nf < 2; nf++) accr[cf][nf] = (f32x4){0.f, 0.f, 0.f, 0.f};
    int cow = w * 32;

    stage(0, 0);
    __syncthreads();
#pragma unroll
    for (int cib = 0; cib < 4; cib++) {
        if (cib < 3) stage(cib + 1, (cib + 1) & 1);
        s16x8 wf[9][2];
#pragma unroll
        for (int pos = 0; pos < 9; pos++)
#pragma unroll
            for (int cf = 0; cf < 2; cf++)
                wf[pos][cf] = *(const s16x8*)&wt[((size_t)(pos * 4 + cib) * C + cow + cf * 16 + l) * 32 + quad * 8];
        const u16* bufc = &in_s[cib & 1][0];
#pragma unroll
        for (int ky = 0; ky < 3; ky++)
#pragma unroll
            for (int kx = 0; kx < 3; kx++) {
                int pos = ky * 3 + kx;
#pragma unroll
                for (int nf = 0; nf < 2; nf++) {
                    s16x8 inf = *(const s16x8*)&bufc[(quad * 102 + ky * 34 + nf * 16 + l + kx) * 8];
                    accr[0][nf] = __builtin_amdgcn_mfma_f32_16x16x32_bf16(wf[pos][0], inf, accr[0][nf], 0, 0, 0);
                    accr[1][nf] = __builtin_amdgcn_mfma_f32_16x16x32_bf16(wf[pos][1], inf, accr[1][nf], 0, 0, 0);
                }
            }
        __syncthreads();
    }

    float g = gamma[0];
    float* ob = out + (size_t)b * C * NN;
    const float* sb = sr + (size_t)b * C * NN;
#pragma unroll
    for (int cf = 0; cf < 2; cf++)
#pragma unroll
        for (int r = 0; r < 4; r++) {
            int co = cow + cf * 16 + quad * 4 + r;
            float bias = bp[co];
#pragma unroll
            for (int nf = 0; nf < 2; nf++) {
                size_t oo = (size_t)co * NN + y * 64 + x0 + nf * 16 + l;
                ob[oo] = sb[oo] + g * (accr[cf][nf][r] + bias);
            }
        }
}

// ---------------------------------------------------------------------------
extern "C" void kernel_launch(void* const* d_in, const int* in_sizes, int n_in,
                              void* d_out, int out_size, void* d_ws, size_t ws_size,
                              hipStream_t stream) {
    const float* sr    = (const float*)d_in[0];
    const float* ctx   = (const float*)d_in[1];
    const float* Wq    = (const float*)d_in[2];
    const float* bq    = (const float*)d_in[3];
    const float* Wk    = (const float*)d_in[4];
    const float* bk    = (const float*)d_in[5];
    const float* Wv    = (const float*)d_in[6];
    const float* bv    = (const float*)d_in[7];
    const float* Wp    = (const float*)d_in[8];
    const float* bp    = (const float*)d_in[9];
    const float* gamma = (const float*)d_in[10];
    float* out = (float*)d_out;

    // ws layout (MB): att_t@0 (4.26 used, 4.5 reserved) |
    //   part@4.5 (32MB, NSPLIT=8) ALIASES ctx_s@4.5(2)+sr_t@6.5(4)+v_s@10.5(1)
    //   (all dead before flash writes part; stream-ordered) |
    //   q_t@36.5 (4) | k_s@40.5 (1) | v_bf@41.5 (4) | lpart@45.5 (0.5) |
    //   wt@46 (0.44) | w_bf@46.5 (0.16) — total 46.7MB (ws >= 256MB per
    //   harness 256MiB poison fills).
    char* wsb = (char*)d_ws;
    u16*   att_t  = (u16*)wsb;
    u16*   part   = (u16*)(wsb + (4u << 20) + (512u << 10));
    u16*   ctx_s  = (u16*)(wsb + (4u << 20) + (512u << 10));
    u16*   sr_t   = (u16*)(wsb + (6u << 20) + (512u << 10));
    u16*   v_s    = (u16*)(wsb + (10u << 20) + (512u << 10));
    u16*   q_t    = (u16*)(wsb + (36u << 20) + (512u << 10));
    u16*   k_s    = (u16*)(wsb + (40u << 20) + (512u << 10));
    u16*   v_bf   = (u16*)(wsb + (41u << 20) + (512u << 10));
    float* lpart  = (float*)(wsb + (45u << 20) + (512u << 10));
    u16*   wt     = (u16*)(wsb + (46u << 20));
    u16*   w_bf   = (u16*)(wsb + (46u << 20) + (512u << 10));

    prep2<<<dim3(2753), 256, 0, stream>>>(ctx, sr, Wq, Wk, Wv, Wp,
                                          ctx_s, sr_t, w_bf, wt, (uint4*)att_t);
    proj_all2<<<dim3(48, NB), 256, 0, stream>>>(sr_t, ctx_s, w_bf, bq, bk, bv,
                                                q_t, k_s, v_s);
    upsample_v<<<dim3(512), 256, 0, stream>>>(v_s, v_bf);
    flash_mfma<<<dim3(1024), 256, 0, stream>>>(q_t, k_s, v_bf, part, lpart);
    flash_combine<<<dim3(64, NB), 256, 0, stream>>>(part, lpart, att_t);
    conv3x3_mfma<<<dim3(512), 256, 0, stream>>>(att_t, wt, bp, sr, gamma, out);
}

// Round 6
// 149.617 us; speedup vs baseline: 1.3075x; 1.3075x over previous
//
#include <hip/hip_runtime.h>
#include <math.h>

// Problem constants
#define NB 4      // batch
#define C  128    // channels (q/k/v/out)
#define CCH 256   // context channels
#define HH 64
#define WW 64
#define NN 4096   // HH*WW
#define NS 1024   // source-resolution pixel count (32*32)
#define HC 32
#define WC 32
#define PP 66     // padded spatial dim for conv input (64 + 2 halo)
#define LOG2E 1.44269504088896f
#define NSPLIT 4  // flash split-K factor

typedef unsigned short u16;
typedef unsigned int uint32;
typedef short s16x8 __attribute__((ext_vector_type(8)));    // 8 bf16 = MFMA A/B frag
typedef float f32x4 __attribute__((ext_vector_type(4)));    // 16x16 MFMA C/D frag
typedef float f32x16 __attribute__((ext_vector_type(16)));  // 32x32 MFMA C/D frag

#if __has_builtin(__builtin_amdgcn_exp2f)
#define EXP2(x) __builtin_amdgcn_exp2f(x)
#else
#define EXP2(x) __expf((x) * 0.69314718056f)
#endif

__device__ __forceinline__ u16 f2bf(float f) {
    uint32 u = __float_as_uint(f);
    u += 0x7fffu + ((u >> 16) & 1u);
    return (u16)(u >> 16);
}
__device__ __forceinline__ float bf2f(u16 h) {
    return __uint_as_float((uint32)h << 16);
}

// ---------------------------------------------------------------------------
// 1) prep2: [0,256) ctx transpose-cast (source res) -> ctx_s bf16 [b][1024][cc]
//    [256,768) sr transpose-cast -> sr_t bf16 [b][4096][C]
//    [768,1664) weight prep   [1664,1729) zero att_t HALO ONLY (combine
//    overwrites the full interior; only the 1-px conv halo ring must be 0 —
//    266 KB instead of 4.46 MB).
// ---------------------------------------------------------------------------
__global__ __launch_bounds__(256) void prep2(const float* __restrict__ ctx,
                                             const float* __restrict__ sr,
                                             const float* __restrict__ Wq,
                                             const float* __restrict__ Wk,
                                             const float* __restrict__ Wv,
                                             const float* __restrict__ Wp,
                                             u16* __restrict__ ctx_s,
                                             u16* __restrict__ sr_t,
                                             u16* __restrict__ wbf,
                                             u16* __restrict__ wt,
                                             uint4* __restrict__ att_z) {
    __shared__ float ls[64 * 65];
    int blk = blockIdx.x;
    int tid = threadIdx.x;

    if (blk < 256) {
        // ctx f32 [b][cc][1024] -> ctx_s bf16 [b][1024][cc], 64x64 tiles
        int idx = blk;
        int n0 = (idx & 15) * 64;
        int ci0 = ((idx >> 4) & 3) * 64;
        int b = idx >> 6;
        const float* inb = ctx + ((size_t)b * CCH + ci0) * NS + n0;
#pragma unroll
        for (int L = 0; L < 4; L++) {
            int fc = tid + L * 256;
            int nc = fc & 15, ci = fc >> 4;
            float4 v = *(const float4*)(inb + (size_t)ci * NS + nc * 4);
            float* d = &ls[ci * 65 + nc * 4];
            d[0] = v.x; d[1] = v.y; d[2] = v.z; d[3] = v.w;
        }
        __syncthreads();
        u16* ob = ctx_s + ((size_t)b * NS + n0) * CCH + ci0;
#pragma unroll
        for (int j = 0; j < 16; j++) {
            int o = tid + j * 256;
            int ci = o & 63, n = o >> 6;
            ob[(size_t)n * CCH + ci] = f2bf(ls[ci * 65 + n]);
        }
    } else if (blk < 768) {
        // sr f32 [b][C][4096] -> sr_t bf16 [b][4096][C]
        int idx = blk - 256;
        int n0 = (idx & 63) * 64;
        int ci0 = ((idx >> 6) & 1) * 64;
        int b = idx >> 7;
        const float* inb = sr + ((size_t)b * C + ci0) * NN + n0;
#pragma unroll
        for (int L = 0; L < 4; L++) {
            int fc = tid + L * 256;
            int nc = fc & 15, ci = fc >> 4;
            float4 v = *(const float4*)(inb + (size_t)ci * NN + nc * 4);
            float* d = &ls[ci * 65 + nc * 4];
            d[0] = v.x; d[1] = v.y; d[2] = v.z; d[3] = v.w;
        }
        __syncthreads();
        u16* ob = sr_t + ((size_t)b * NN + n0) * C + ci0;
#pragma unroll
        for (int j = 0; j < 16; j++) {
            int o = tid + j * 256;
            int ci = o & 63, n = o >> 6;
            ob[(size_t)n * C + ci] = f2bf(ls[ci * 65 + n]);
        }
    } else if (blk < 1664) {
        int i = (blk - 768) * 256 + tid;   // 0..229375
        if (i < 81920) {
            float v;
            if (i < 16384) v = Wq[i] * LOG2E;
            else if (i < 49152) v = Wk[i - 16384];
            else v = Wv[i - 49152];
            wbf[i] = f2bf(v);
        } else {
            int idx = i - 81920;
            int ciin = idx & 31;
            int co = (idx >> 5) & 127;
            int cb = (idx >> 12) & 3;
            int pos = idx >> 14;
            int ky = pos / 3, kx = pos - ky * 3;
            int ci = cb * 32 + ciin;
            wt[idx] = f2bf(Wp[((size_t)(co * C + ci) * 3 + ky) * 3 + kx]);
        }
    } else {
        // zero att_t halo ring only: per b, rows y=0,65 (1056 uint4 each)
        // + cols x=0,65 for y=1..64 (16 uint4 per (y,x)) = 4160 uint4/b.
        int i = (blk - 1664) * 256 + tid;   // 0..16639
        if (i < 16640) {
            int b = i / 4160;
            int r = i - b * 4160;
            uint4* ab = att_z + (size_t)b * (PP * PP * C / 8);
            if (r < 2112) {
                int y = (r >= 1056) ? 65 : 0;
                int off = (r >= 1056) ? r - 1056 : r;
                ab[(size_t)y * (PP * C / 8) + off] = make_uint4(0, 0, 0, 0);
            } else {
                int r2 = r - 2112;
                int y = 1 + (r2 >> 5);
                int x = (r2 & 16) ? 65 : 0;
                int o = r2 & 15;
                ab[((size_t)y * PP + x) * (C / 8) + o] = make_uint4(0, 0, 0, 0);
            }
        }
    }
}

// ---------------------------------------------------------------------------
// 2) proj_all2: x<32 -> q projection (N=4096, Cin=128, sr_t);
//               x>=32 -> K AND V from one staged ctx_s tile (N=1024, Cin=256).
// ---------------------------------------------------------------------------
__global__ __launch_bounds__(256) void proj_all2(const u16* __restrict__ sr_t,
                                                 const u16* __restrict__ ctx_s,
                                                 const u16* __restrict__ wbf,
                                                 const float* __restrict__ bq,
                                                 const float* __restrict__ bk,
                                                 const float* __restrict__ bv,
                                                 u16* __restrict__ q_t,
                                                 u16* __restrict__ k_s,
                                                 u16* __restrict__ v_s) {
    __shared__ u16 xs[128 * 64];      // 16 KB (kv uses first 8 KB)
    __shared__ u16 wsm[2][128 * 64];  // 32 KB
    int b = blockIdx.y;
    int tid = threadIdx.x;
    int w = tid >> 6, lane = tid & 63, l31 = lane & 31, half = lane >> 5;
    int xh = w >> 1, wh = w & 1;

    if (blockIdx.x < 32) {
        // ---- Q: 128 n x 128 co, Cin=128 ----
        int n0 = blockIdx.x * 128;
        const u16* xb = sr_t + (size_t)b * NN * C;
        f32x16 acc[2][2];
#pragma unroll
        for (int xt = 0; xt < 2; xt++)
#pragma unroll
            for (int wt2 = 0; wt2 < 2; wt2++)
#pragma unroll
                for (int i = 0; i < 16; i++) acc[xt][wt2][i] = 0.f;
        for (int c0i = 0; c0i < 2; c0i++) {
            int c0 = c0i * 64;
            __syncthreads();
#pragma unroll
            for (int t = 0; t < 4; t++) {
                int CI = t * 256 + tid;
                int row = CI >> 3, sl = CI & 7;
                int lc = sl ^ (row & 7);
                __builtin_amdgcn_global_load_lds(
                    (const __attribute__((address_space(1))) void*)(xb + (size_t)(n0 + row) * C + c0 + lc * 8),
                    (__attribute__((address_space(3))) void*)&xs[(size_t)CI * 8], 16, 0, 0);
            }
#pragma unroll
            for (int t = 0; t < 4; t++) {
                int CI = t * 256 + tid;
                int co = CI >> 3, sl = CI & 7;
                int lc = sl ^ (co & 7);
                __builtin_amdgcn_global_load_lds(
                    (const __attribute__((address_space(1))) void*)(wbf + (size_t)co * C + c0 + lc * 8),
                    (__attribute__((address_space(3))) void*)&wsm[0][(size_t)CI * 8], 16, 0, 0);
            }
            __syncthreads();
#pragma unroll
            for (int kg = 0; kg < 4; kg++) {
                int pc = ((kg * 2 + half) ^ (l31 & 7)) * 8;
                s16x8 xf[2], wf2[2];
#pragma unroll
                for (int xt = 0; xt < 2; xt++)
                    xf[xt] = *(const s16x8*)&xs[(xh * 64 + xt * 32 + l31) * 64 + pc];
#pragma unroll
                for (int wt2 = 0; wt2 < 2; wt2++)
                    wf2[wt2] = *(const s16x8*)&wsm[0][(wh * 64 + wt2 * 32 + l31) * 64 + pc];
#pragma unroll
                for (int xt = 0; xt < 2; xt++)
#pragma unroll
                    for (int wt2 = 0; wt2 < 2; wt2++)
                        acc[xt][wt2] = __builtin_amdgcn_mfma_f32_32x32x16_bf16(xf[xt], wf2[wt2], acc[xt][wt2], 0, 0, 0);
            }
        }
        u16* ot = q_t + (size_t)b * NN * C;
        float bv2[2];
#pragma unroll
        for (int wt2 = 0; wt2 < 2; wt2++) bv2[wt2] = bq[wh * 64 + wt2 * 32 + l31] * LOG2E;
#pragma unroll
        for (int xt = 0; xt < 2; xt++)
#pragma unroll
            for (int r = 0; r < 16; r++) {
                int n = n0 + xh * 64 + xt * 32 + (r & 3) + 8 * (r >> 2) + 4 * half;
#pragma unroll
                for (int wt2 = 0; wt2 < 2; wt2++)
                    ot[(size_t)n * C + wh * 64 + wt2 * 32 + l31] = f2bf(acc[xt][wt2][r] + bv2[wt2]);
            }
    } else {
        // ---- K & V: 64 source px x 128 co, Cin=256, ctx staged once ----
        int n0 = (blockIdx.x - 32) * 64;
        const u16* xb = ctx_s + (size_t)b * NS * CCH;
        const u16* wkb = wbf + 16384;
        const u16* wvb = wbf + 49152;
        f32x16 acck[2], accv[2];   // [wt2]; wave: n-tile xh*32, co wh*64+wt2*32
#pragma unroll
        for (int wt2 = 0; wt2 < 2; wt2++)
#pragma unroll
            for (int i = 0; i < 16; i++) { acck[wt2][i] = 0.f; accv[wt2][i] = 0.f; }
        for (int c0i = 0; c0i < 4; c0i++) {
            int c0 = c0i * 64;
            __syncthreads();
#pragma unroll
            for (int t = 0; t < 2; t++) {          // 64 rows x 8 chunks
                int CI = t * 256 + tid;
                int row = CI >> 3, sl = CI & 7;
                int lc = sl ^ (row & 7);
                __builtin_amdgcn_global_load_lds(
                    (const __attribute__((address_space(1))) void*)(xb + (size_t)(n0 + row) * CCH + c0 + lc * 8),
                    (__attribute__((address_space(3))) void*)&xs[(size_t)CI * 8], 16, 0, 0);
            }
#pragma unroll
            for (int t = 0; t < 4; t++) {
                int CI = t * 256 + tid;
                int co = CI >> 3, sl = CI & 7;
                int lc = sl ^ (co & 7);
                __builtin_amdgcn_global_load_lds(
                    (const __attribute__((address_space(1))) void*)(wkb + (size_t)co * CCH + c0 + lc * 8),
                    (__attribute__((address_space(3))) void*)&wsm[0][(size_t)CI * 8], 16, 0, 0);
            }
#pragma unroll
            for (int t = 0; t < 4; t++) {
                int CI = t * 256 + tid;
                int co = CI >> 3, sl = CI & 7;
                int lc = sl ^ (co & 7);
                __builtin_amdgcn_global_load_lds(
                    (const __attribute__((address_space(1))) void*)(wvb + (size_t)co * CCH + c0 + lc * 8),
                    (__attribute__((address_space(3))) void*)&wsm[1][(size_t)CI * 8], 16, 0, 0);
            }
            __syncthreads();
#pragma unroll
            for (int kg = 0; kg < 4; kg++) {
                int pc = ((kg * 2 + half) ^ (l31 & 7)) * 8;
                s16x8 xf = *(const s16x8*)&xs[(xh * 32 + l31) * 64 + pc];
                s16x8 wfk[2], wfv[2];
#pragma unroll
                for (int wt2 = 0; wt2 < 2; wt2++) {
                    wfk[wt2] = *(const s16x8*)&wsm[0][(wh * 64 + wt2 * 32 + l31) * 64 + pc];
                    wfv[wt2] = *(const s16x8*)&wsm[1][(wh * 64 + wt2 * 32 + l31) * 64 + pc];
                }
#pragma unroll
                for (int wt2 = 0; wt2 < 2; wt2++) {
                    acck[wt2] = __builtin_amdgcn_mfma_f32_32x32x16_bf16(xf, wfk[wt2], acck[wt2], 0, 0, 0);
                    accv[wt2] = __builtin_amdgcn_mfma_f32_32x32x16_bf16(wfv[wt2], xf, accv[wt2], 0, 0, 0);
                }
            }
        }
        // K epilogue: T-layout k_s[b][n][co]
        u16* ok = k_s + (size_t)b * NS * C;
#pragma unroll
        for (int wt2 = 0; wt2 < 2; wt2++) {
            float bvk = bk[wh * 64 + wt2 * 32 + l31];
#pragma unroll
            for (int r = 0; r < 16; r++) {
                int n = n0 + xh * 32 + (r & 3) + 8 * (r >> 2) + 4 * half;
                ok[(size_t)n * C + wh * 64 + wt2 * 32 + l31] = f2bf(acck[wt2][r] + bvk);
            }
        }
        // V epilogue: N-layout v_s[b][co][n]
        u16* ov = v_s + (size_t)b * C * NS;
#pragma unroll
        for (int wt2 = 0; wt2 < 2; wt2++)
#pragma unroll
            for (int r = 0; r < 16; r++) {
                int co = wh * 64 + wt2 * 32 + (r & 3) + 8 * (r >> 2) + 4 * half;
                ov[(size_t)co * NS + n0 + xh * 32 + l31] = f2bf(accv[wt2][r] + bv[co]);
            }
    }
}

// ---------------------------------------------------------------------------
// 3) upsample_v: v_s [b][C][1024] -> v [b][C][4096]
//    (bilinear, half-pixel centers, clamped — commutes with 1x1 conv)
// ---------------------------------------------------------------------------
__global__ __launch_bounds__(256) void upsample_v(const u16* __restrict__ v_s,
                                                  u16* __restrict__ v_bf) {
    __shared__ u16 lsv[NS];
    int idx = blockIdx.x;
    int tid = threadIdx.x;
    // one (b,c) plane: 1024 -> 4096
    int c = idx & 127, b = idx >> 7;
    const u16* vp = v_s + ((size_t)b * C + c) * NS;
    if (tid < 128) *(uint4*)&lsv[tid * 8] = *(const uint4*)(vp + tid * 8);
    __syncthreads();
    u16* ob = v_bf + ((size_t)b * C + c) * NN;
#pragma unroll
    for (int j = 0; j < 16; j++) {
        int n = tid + j * 256;
        int y = n >> 6, x = n & 63;
        float sy = y * 0.5f - 0.25f;
        float sx = x * 0.5f - 0.25f;
        int y0 = (int)floorf(sy), x0 = (int)floorf(sx);
        float wy = sy - (float)y0, wx = sx - (float)x0;
        int y0c = y0 < 0 ? 0 : y0;
        int y1c = (y0 + 1 > HC - 1) ? HC - 1 : y0 + 1;
        int x0c = x0 < 0 ? 0 : x0;
        int x1c = (x0 + 1 > WC - 1) ? WC - 1 : x0 + 1;
        float v00 = bf2f(lsv[y0c * WC + x0c]), v01 = bf2f(lsv[y0c * WC + x1c]);
        float v10 = bf2f(lsv[y1c * WC + x0c]), v11 = bf2f(lsv[y1c * WC + x1c]);
        ob[n] = f2bf((1.f - wy) * ((1.f - wx) * v00 + wx * v01)
                   +        wy  * ((1.f - wx) * v10 + wx * v11));
    }
}

// ---------------------------------------------------------------------------
// 4) Flash attention v11 (the 150.2us champion, byte-identical):
//    score-space bilinear upsampling. Per split (16 fine rows), rolling
//    2-row window of SOURCE score tiles (32 src px x 32 q) in registers;
//    per y: y-lerp + x-stencil (0.25/0.75) + exp2 produces p directly in
//    the PV B-fragment layout; PV at fine res from double-buffered LDS V.
//    Score tiles computed one iteration ahead (sC) from 3 rotating 8KB
//    source-K row buffers so the 8-MFMA chain stays off the critical path
//    (v15 proved removing it costs 18us).
// ---------------------------------------------------------------------------
__global__ __launch_bounds__(256, 2) void flash_mfma(const u16* __restrict__ qt_p,
                                                     const u16* __restrict__ ks_p,
                                                     const u16* __restrict__ vt_p,
                                                     u16* __restrict__ part,
                                                     float* __restrict__ lpart) {
    __shared__ u16 ksr[3][32 * 128];   // rotating source-K row buffers (8 KB each)
    __shared__ u16 vs[2][128 * 64];    // V double buffer (16 KB each)

    int ib = blockIdx.x;
    int b = (ib & 7) >> 1;
    int rest = ((ib >> 3) << 1) | (ib & 1);
    int qtile = rest >> 2;
    int split = rest & 3;
    int n0 = qtile * 128;
    int tid = threadIdx.x;
    int w = tid >> 6, lane = tid & 63, l31 = lane & 31, half = lane >> 5;

    const u16* qtb = qt_p + (size_t)b * NN * C;
    const u16* ksb = ks_p + (size_t)b * NS * C;
    const u16* vtb = vt_p + (size_t)b * C * NN;

    // stage source-K row r (32 px x 128 ch = 8 KB) into ksr[buf]
    auto stageKrow = [&](int buf, int r) {
#pragma unroll
        for (int t = 0; t < 2; t++) {
            int CI = t * 256 + tid;            // chunk 0..511
            int row = CI >> 4;                 // src px within row (jx)
            int lc = (CI & 15) ^ (row & 15);
            __builtin_amdgcn_global_load_lds(
                (const __attribute__((address_space(1))) void*)(ksb + (size_t)(r * 32 + row) * C + lc * 8),
                (__attribute__((address_space(3))) void*)&ksr[buf][(size_t)CI * 8], 16, 0, 0);
        }
    };
    auto stageV = [&](int buf, int m0) {
#pragma unroll
        for (int t = 0; t < 4; t++) {
            int CI = (w * 4 + t) * 64 + lane;
            int c = CI >> 3;
            int lc = (CI & 7) ^ (c & 7);
            __builtin_amdgcn_global_load_lds(
                (const __attribute__((address_space(1))) void*)(vtb + (size_t)c * NN + m0 + lc * 8),
                (__attribute__((address_space(3))) void*)&vs[buf][(w * 4 + t) * 512], 16, 0, 0);
        }
    };

    int qrow = n0 + w * 32 + l31;
    s16x8 qf[8];
#pragma unroll
    for (int kg = 0; kg < 8; kg++)
        qf[kg] = *(const s16x8*)(qtb + (size_t)qrow * C + kg * 16 + half * 8);

    // score tile: rows = 32 src px of one source row, cols = 32 q
    auto scoreTile = [&](int buf) {
        f32x16 st;
#pragma unroll
        for (int i = 0; i < 16; i++) st[i] = 0.f;
        const u16* kb = &ksr[buf][0];
#pragma unroll
        for (int kg = 0; kg < 8; kg++) {
            int pc = ((kg * 2 + half) ^ (l31 & 15)) * 8;
            s16x8 kf = *(const s16x8*)&kb[l31 * 128 + pc];
            st = __builtin_amdgcn_mfma_f32_32x32x16_bf16(kf, qf[kg], st, 0, 0, 0);
        }
        return st;
    };

    int m_base = split * 1024;
    int j0 = split * 8;   // first source row of this split's window

    // prologue: rows (j0-1 clamp, j0) for y=16*split, plus j0+1 for it=1
    stageKrow(0, split == 0 ? 0 : j0 - 1);
    stageKrow(1, j0);
    stageKrow(2, j0 + 1);              // j0+1 <= 25 always
    stageV(0, m_base);
    __syncthreads();
    f32x16 sA = scoreTile(0);          // score(rlo)
    f32x16 sB = scoreTile(1);          // score(rhi)
    f32x16 sC;                          // next row's tile (computed at even it)

    f32x16 oacc[4];
#pragma unroll
    for (int mt = 0; mt < 4; mt++)
#pragma unroll
        for (int i = 0; i < 16; i++) oacc[mt][i] = 0.f;
    float lsum = 0.f;

#pragma unroll 2
    for (int it = 0; it < 16; it++) {    // y = 16*split + it
        int buf = it & 1;
        int m0 = m_base + it * 64;
        if (it < 15) {
            stageV(buf ^ 1, m0 + 64);
            if (it & 1) {                         // stage row for compute at it+1
                int rs = j0 + 2 + (it >> 1);
                if (rs <= 31) stageKrow((it >> 1) % 3, rs);
            }
        }
        if (!(it & 1)) {                          // compute next tile ahead of use
            int rn = j0 + 1 + (it >> 1);
            if (rn <= 31) sC = scoreTile((2 + (it >> 1)) % 3);
        } else {                                  // window advance: rows (j, j+1)
            sA = sB;
            int rn = j0 + 1 + (it >> 1);
            if (rn <= 31) sB = sC;                // else clamp: keep row 31
        }

        // y-lerp: even y -> (0.25,0.75), odd y -> (0.75,0.25) on (rlo,rhi)
        float wB = (it & 1) ? 0.25f : 0.75f;
        float wA = 1.0f - wB;
        float cc[16];
#pragma unroll
        for (int i = 0; i < 16; i++) cc[i] = wA * sA[i] + wB * sB[i];

        // boundary exchange across lane-halves (rows interleave in blocks of 4)
        float xr0  = __shfl_xor(cc[0], 32);
        float xr3  = __shfl_xor(cc[3], 32);
        float xr4  = __shfl_xor(cc[4], 32);
        float xr7  = __shfl_xor(cc[7], 32);
        float xr8  = __shfl_xor(cc[8], 32);
        float xr11 = __shfl_xor(cc[11], 32);
        float xr12 = __shfl_xor(cc[12], 32);
        float xr15 = __shfl_xor(cc[15], 32);
        float d0s[4], d5s[4];
        d0s[0] = half ? xr3  : cc[0];   // x-block edge rows 4xb-1 (clamped at 0)
        d0s[1] = half ? xr7  : xr3;
        d0s[2] = half ? xr11 : xr7;
        d0s[3] = half ? xr15 : xr11;
        d5s[0] = half ? xr4  : xr0;     // rows 4xb+4 (clamped at 31)
        d5s[1] = half ? xr8  : xr4;
        d5s[2] = half ? xr12 : xr8;
        d5s[3] = half ? cc[15] : xr12;

        const u16* vsb = &vs[buf][0];
#pragma unroll
        for (int s = 0; s < 4; s++) {   // x-block xb = 2*s + half; x = 8*xb..+7
            float d0 = d0s[s], d1 = cc[4 * s], d2 = cc[4 * s + 1];
            float d3 = cc[4 * s + 2], d4 = cc[4 * s + 3], d5 = d5s[s];
            float e1 = 0.75f * d1, e2 = 0.75f * d2, e3 = 0.75f * d3, e4 = 0.75f * d4;
            float p0 = EXP2(fmaf(0.25f, d0, e1));
            float p1 = EXP2(fmaf(0.25f, d2, e1));
            float p2 = EXP2(fmaf(0.25f, d1, e2));
            float p3 = EXP2(fmaf(0.25f, d3, e2));
            float p4 = EXP2(fmaf(0.25f, d2, e3));
            float p5 = EXP2(fmaf(0.25f, d4, e3));
            float p6 = EXP2(fmaf(0.25f, d3, e4));
            float p7 = EXP2(fmaf(0.25f, d5, e4));
            lsum += ((p0 + p1) + (p2 + p3)) + ((p4 + p5) + (p6 + p7));
            union { uint32 u[4]; s16x8 v; } pu;
            pu.u[0] = __builtin_amdgcn_perm(__float_as_uint(p1), __float_as_uint(p0), 0x07060302u);
            pu.u[1] = __builtin_amdgcn_perm(__float_as_uint(p3), __float_as_uint(p2), 0x07060302u);
            pu.u[2] = __builtin_amdgcn_perm(__float_as_uint(p5), __float_as_uint(p4), 0x07060302u);
            pu.u[3] = __builtin_amdgcn_perm(__float_as_uint(p7), __float_as_uint(p6), 0x07060302u);
            int pcv = ((s * 2 + half) ^ (l31 & 7)) * 8;
#pragma unroll
            for (int mt = 0; mt < 4; mt++) {
                s16x8 vf = *(const s16x8*)&vsb[(mt * 32 + l31) * 64 + pcv];
                oacc[mt] = __builtin_amdgcn_mfma_f32_32x32x16_bf16(vf, pu.v, oacc[mt], 0, 0, 0);
            }
        }
        __syncthreads();
    }

    float lt = lsum + __shfl_xor(lsum, 32);
    if (half == 0) lpart[(size_t)split * NB * NN + (size_t)b * NN + qrow] = lt;
    u16* pb = part + ((size_t)split * NB + b) * (size_t)C * NN;
#pragma unroll
    for (int mt = 0; mt < 4; mt++)
#pragma unroll
        for (int r = 0; r < 16; r++) {
            int c = mt * 32 + (r & 3) + 8 * (r >> 2) + 4 * half;
            pb[(size_t)c * NN + n0 + w * 32 + l31] = f2bf(oacc[mt][r]);
        }
}

// ---------------------------------------------------------------------------
// 5) Combine (unchanged).
// ---------------------------------------------------------------------------
__global__ __launch_bounds__(256) void flash_combine(const u16* __restrict__ part,
                                                     const float* __restrict__ lpart,
                                                     u16* __restrict__ att_t) {
    __shared__ u16 ts[128 * 66];
    __shared__ float linv[64];
    int b = blockIdx.y;
    int nt = blockIdx.x;
    int n0 = nt * 64;
    int tid = threadIdx.x;
    if (tid < 64) {
        float s = 0.f;
#pragma unroll
        for (int sp = 0; sp < NSPLIT; sp++)
            s += lpart[(size_t)sp * NB * NN + (size_t)b * NN + n0 + tid];
        linv[tid] = 1.0f / s;
    }
    __syncthreads();
#pragma unroll
    for (int j = 0; j < 32; j++) {
        int e = tid + j * 256;
        int n = e & 63, c = e >> 6;
        float o = 0.f;
#pragma unroll
        for (int sp = 0; sp < NSPLIT; sp++)
            o += bf2f(part[((size_t)sp * NB + b) * (size_t)C * NN + (size_t)c * NN + n0 + n]);
        ts[c * 66 + n] = f2bf(o * linv[n]);
    }
    __syncthreads();
    u16* ob = att_t + ((size_t)b * PP * PP + (size_t)(nt + 1) * PP + 1) * C;
#pragma unroll
    for (int j = 0; j < 32; j++) {
        int o = tid + j * 256;
        int c = o & 127, n = o >> 7;
        ob[(size_t)n * C + c] = ts[c * 66 + n];
    }
}

// ---------------------------------------------------------------------------
// 6) Conv3x3 MFMA + residual (unchanged).
// ---------------------------------------------------------------------------
__global__ __launch_bounds__(256) void conv3x3_mfma(const u16* __restrict__ att_t,
                                                    const u16* __restrict__ wt,
                                                    const float* __restrict__ bp,
                                                    const float* __restrict__ sr,
                                                    const float* __restrict__ gamma,
                                                    float* __restrict__ out) {
    __shared__ u16 in_s[2][4 * 102 * 8];
    int ib = blockIdx.x;
    int b = (ib & 7) >> 1;
    int rr = ((ib >> 3) << 1) | (ib & 1);
    int y = rr >> 1;
    int x0 = (rr & 1) * 32;
    int tid = threadIdx.x;
    int w = tid >> 6, lane = tid & 63, l = tid & 15, quad = (tid >> 4) & 3;
    const u16* ab = att_t + (size_t)b * (PP * PP * C);

    auto stage = [&](int cib, int bufi) {
        u16* base = &in_s[bufi][w * 102 * 8];
        const u16* gsrc = ab + cib * 32 + w * 8;
#pragma unroll
        for (int t = 0; t < 2; t++) {
            int idx = t * 64 + lane;
            int r = idx / 34, xp = idx - r * 34;
            if (t == 0 || lane < 38)
                __builtin_amdgcn_global_load_lds(
                    (const __attribute__((address_space(1))) void*)(gsrc + (size_t)((y + r) * PP + x0 + xp) * C),
                    (__attribute__((address_space(3))) void*)(base + (size_t)t * 64 * 8), 16, 0, 0);
        }
    };

    f32x4 accr[2][2];
#pragma unroll
    for (int cf = 0; cf < 2; cf++)
#pragma unroll
        for (int nf = 0; nf < 2; nf++) accr[cf][nf] = (f32x4){0.f, 0.f, 0.f, 0.f};
    int cow = w * 32;

    stage(0, 0);
    __syncthreads();
#pragma unroll
    for (int cib = 0; cib < 4; cib++) {
        if (cib < 3) stage(cib + 1, (cib + 1) & 1);
        s16x8 wf[9][2];
#pragma unroll
        for (int pos = 0; pos < 9; pos++)
#pragma unroll
            for (int cf = 0; cf < 2; cf++)
                wf[pos][cf] = *(const s16x8*)&wt[((size_t)(pos * 4 + cib) * C + cow + cf * 16 + l) * 32 + quad * 8];
        const u16* bufc = &in_s[cib & 1][0];
#pragma unroll
        for (int ky = 0; ky < 3; ky++)
#pragma unroll
            for (int kx = 0; kx < 3; kx++) {
                int pos = ky * 3 + kx;
#pragma unroll
                for (int nf = 0; nf < 2; nf++) {
                    s16x8 inf = *(const s16x8*)&bufc[(quad * 102 + ky * 34 + nf * 16 + l + kx) * 8];
                    accr[0][nf] = __builtin_amdgcn_mfma_f32_16x16x32_bf16(wf[pos][0], inf, accr[0][nf], 0, 0, 0);
                    accr[1][nf] = __builtin_amdgcn_mfma_f32_16x16x32_bf16(wf[pos][1], inf, accr[1][nf], 0, 0, 0);
                }
            }
        __syncthreads();
    }

    float g = gamma[0];
    float* ob = out + (size_t)b * C * NN;
    const float* sb = sr + (size_t)b * C * NN;
#pragma unroll
    for (int cf = 0; cf < 2; cf++)
#pragma unroll
        for (int r = 0; r < 4; r++) {
            int co = cow + cf * 16 + quad * 4 + r;
            float bias = bp[co];
#pragma unroll
            for (int nf = 0; nf < 2; nf++) {
                size_t oo = (size_t)co * NN + y * 64 + x0 + nf * 16 + l;
                ob[oo] = sb[oo] + g * (accr[cf][nf][r] + bias);
            }
        }
}

// ---------------------------------------------------------------------------
extern "C" void kernel_launch(void* const* d_in, const int* in_sizes, int n_in,
                              void* d_out, int out_size, void* d_ws, size_t ws_size,
                              hipStream_t stream) {
    const float* sr    = (const float*)d_in[0];
    const float* ctx   = (const float*)d_in[1];
    const float* Wq    = (const float*)d_in[2];
    const float* bq    = (const float*)d_in[3];
    const float* Wk    = (const float*)d_in[4];
    const float* bk    = (const float*)d_in[5];
    const float* Wv    = (const float*)d_in[6];
    const float* bv    = (const float*)d_in[7];
    const float* Wp    = (const float*)d_in[8];
    const float* bp    = (const float*)d_in[9];
    const float* gamma = (const float*)d_in[10];
    float* out = (float*)d_out;

    // ws layout (MB): att_t@0 | part@5 (16MB) | lpart@21 | ctx_s@22 (2MB) |
    //   sr_t@25 (4MB) | q_t@29 (4MB) | k_s@33 (1MB) | v_s@34 (1MB) |
    //   v_bf@39 (4MB) | wt@43 | w_bf@43.5
    char* wsb = (char*)d_ws;
    u16*   att_t  = (u16*)wsb;
    u16*   part   = (u16*)(wsb + (5u << 20));
    float* lpart  = (float*)(wsb + (21u << 20));
    u16*   ctx_s  = (u16*)(wsb + (22u << 20));
    u16*   sr_t   = (u16*)(wsb + (25u << 20));
    u16*   q_t    = (u16*)(wsb + (29u << 20));
    u16*   k_s    = (u16*)(wsb + (33u << 20));
    u16*   v_s    = (u16*)(wsb + (34u << 20));
    u16*   v_bf   = (u16*)(wsb + (39u << 20));
    u16*   wt     = (u16*)(wsb + (43u << 20));
    u16*   w_bf   = (u16*)(wsb + (43u << 20) + (512u << 10));

    prep2<<<dim3(1729), 256, 0, stream>>>(ctx, sr, Wq, Wk, Wv, Wp,
                                          ctx_s, sr_t, w_bf, wt, (uint4*)att_t);
    proj_all2<<<dim3(48, NB), 256, 0, stream>>>(sr_t, ctx_s, w_bf, bq, bk, bv,
                                                q_t, k_s, v_s);
    upsample_v<<<dim3(512), 256, 0, stream>>>(v_s, v_bf);
    flash_mfma<<<dim3(512), 256, 0, stream>>>(q_t, k_s, v_bf, part, lpart);
    flash_combine<<<dim3(64, NB), 256, 0, stream>>>(part, lpart, att_t);
    conv3x3_mfma<<<dim3(512), 256, 0, stream>>>(att_t, wt, bp, sr, gamma, out);
}

// Round 8
// 146.964 us; speedup vs baseline: 1.3311x; 1.0180x over previous
//
#include <hip/hip_runtime.h>
#include <math.h>

// Problem constants
#define NB 4      // batch
#define C  128    // channels (q/k/v/out)
#define CCH 256   // context channels
#define HH 64
#define WW 64
#define NN 4096   // HH*WW
#define NS 1024   // source-resolution pixel count (32*32)
#define HC 32
#define WC 32
#define PP 66     // padded spatial dim for conv input (64 + 2 halo)
#define LOG2E 1.44269504088896f
#define NSPLIT 4  // flash split-K factor

typedef unsigned short u16;
typedef unsigned int uint32;
typedef short s16x8 __attribute__((ext_vector_type(8)));    // 8 bf16 = MFMA A/B frag
typedef float f32x4 __attribute__((ext_vector_type(4)));    // 16x16 MFMA C/D frag
typedef float f32x16 __attribute__((ext_vector_type(16)));  // 32x32 MFMA C/D frag

#if __has_builtin(__builtin_amdgcn_exp2f)
#define EXP2(x) __builtin_amdgcn_exp2f(x)
#else
#define EXP2(x) __expf((x) * 0.69314718056f)
#endif

__device__ __forceinline__ u16 f2bf(float f) {
    uint32 u = __float_as_uint(f);
    u += 0x7fffu + ((u >> 16) & 1u);
    return (u16)(u >> 16);
}
__device__ __forceinline__ float bf2f(u16 h) {
    return __uint_as_float((uint32)h << 16);
}

// ---------------------------------------------------------------------------
// 1) prep2: [0,256) ctx transpose-cast (source res) -> ctx_s bf16 [b][1024][cc]
//    [256,768) sr transpose-cast -> sr_t bf16 [b][4096][C]
//    [768,1664) weight prep   [1664,1729) zero att_t HALO ONLY (combine
//    overwrites the full interior; only the 1-px conv halo ring must be 0).
// ---------------------------------------------------------------------------
__global__ __launch_bounds__(256) void prep2(const float* __restrict__ ctx,
                                             const float* __restrict__ sr,
                                             const float* __restrict__ Wq,
                                             const float* __restrict__ Wk,
                                             const float* __restrict__ Wv,
                                             const float* __restrict__ Wp,
                                             u16* __restrict__ ctx_s,
                                             u16* __restrict__ sr_t,
                                             u16* __restrict__ wbf,
                                             u16* __restrict__ wt,
                                             uint4* __restrict__ att_z) {
    __shared__ float ls[64 * 65];
    int blk = blockIdx.x;
    int tid = threadIdx.x;

    if (blk < 256) {
        // ctx f32 [b][cc][1024] -> ctx_s bf16 [b][1024][cc], 64x64 tiles
        int idx = blk;
        int n0 = (idx & 15) * 64;
        int ci0 = ((idx >> 4) & 3) * 64;
        int b = idx >> 6;
        const float* inb = ctx + ((size_t)b * CCH + ci0) * NS + n0;
#pragma unroll
        for (int L = 0; L < 4; L++) {
            int fc = tid + L * 256;
            int nc = fc & 15, ci = fc >> 4;
            float4 v = *(const float4*)(inb + (size_t)ci * NS + nc * 4);
            float* d = &ls[ci * 65 + nc * 4];
            d[0] = v.x; d[1] = v.y; d[2] = v.z; d[3] = v.w;
        }
        __syncthreads();
        u16* ob = ctx_s + ((size_t)b * NS + n0) * CCH + ci0;
#pragma unroll
        for (int j = 0; j < 16; j++) {
            int o = tid + j * 256;
            int ci = o & 63, n = o >> 6;
            ob[(size_t)n * CCH + ci] = f2bf(ls[ci * 65 + n]);
        }
    } else if (blk < 768) {
        // sr f32 [b][C][4096] -> sr_t bf16 [b][4096][C]
        int idx = blk - 256;
        int n0 = (idx & 63) * 64;
        int ci0 = ((idx >> 6) & 1) * 64;
        int b = idx >> 7;
        const float* inb = sr + ((size_t)b * C + ci0) * NN + n0;
#pragma unroll
        for (int L = 0; L < 4; L++) {
            int fc = tid + L * 256;
            int nc = fc & 15, ci = fc >> 4;
            float4 v = *(const float4*)(inb + (size_t)ci * NN + nc * 4);
            float* d = &ls[ci * 65 + nc * 4];
            d[0] = v.x; d[1] = v.y; d[2] = v.z; d[3] = v.w;
        }
        __syncthreads();
        u16* ob = sr_t + ((size_t)b * NN + n0) * C + ci0;
#pragma unroll
        for (int j = 0; j < 16; j++) {
            int o = tid + j * 256;
            int ci = o & 63, n = o >> 6;
            ob[(size_t)n * C + ci] = f2bf(ls[ci * 65 + n]);
        }
    } else if (blk < 1664) {
        int i = (blk - 768) * 256 + tid;   // 0..229375
        if (i < 81920) {
            float v;
            if (i < 16384) v = Wq[i] * LOG2E;
            else if (i < 49152) v = Wk[i - 16384];
            else v = Wv[i - 49152];
            wbf[i] = f2bf(v);
        } else {
            int idx = i - 81920;
            int ciin = idx & 31;
            int co = (idx >> 5) & 127;
            int cb = (idx >> 12) & 3;
            int pos = idx >> 14;
            int ky = pos / 3, kx = pos - ky * 3;
            int ci = cb * 32 + ciin;
            wt[idx] = f2bf(Wp[((size_t)(co * C + ci) * 3 + ky) * 3 + kx]);
        }
    } else {
        // zero att_t halo ring only: per b, rows y=0,65 (1056 uint4 each)
        // + cols x=0,65 for y=1..64 (16 uint4 per (y,x)) = 4160 uint4/b.
        int i = (blk - 1664) * 256 + tid;   // 0..16639
        if (i < 16640) {
            int b = i / 4160;
            int r = i - b * 4160;
            uint4* ab = att_z + (size_t)b * (PP * PP * C / 8);
            if (r < 2112) {
                int y = (r >= 1056) ? 65 : 0;
                int off = (r >= 1056) ? r - 1056 : r;
                ab[(size_t)y * (PP * C / 8) + off] = make_uint4(0, 0, 0, 0);
            } else {
                int r2 = r - 2112;
                int y = 1 + (r2 >> 5);
                int x = (r2 & 16) ? 65 : 0;
                int o = r2 & 15;
                ab[((size_t)y * PP + x) * (C / 8) + o] = make_uint4(0, 0, 0, 0);
            }
        }
    }
}

// ---------------------------------------------------------------------------
// 2) proj_all2: x<32 -> q projection (N=4096, Cin=128, sr_t);
//               x>=32 -> K AND V from one staged ctx_s tile (N=1024, Cin=256).
// ---------------------------------------------------------------------------
__global__ __launch_bounds__(256) void proj_all2(const u16* __restrict__ sr_t,
                                                 const u16* __restrict__ ctx_s,
                                                 const u16* __restrict__ wbf,
                                                 const float* __restrict__ bq,
                                                 const float* __restrict__ bk,
                                                 const float* __restrict__ bv,
                                                 u16* __restrict__ q_t,
                                                 u16* __restrict__ k_s,
                                                 u16* __restrict__ v_s) {
    __shared__ u16 xs[128 * 64];      // 16 KB (kv uses first 8 KB)
    __shared__ u16 wsm[2][128 * 64];  // 32 KB
    int b = blockIdx.y;
    int tid = threadIdx.x;
    int w = tid >> 6, lane = tid & 63, l31 = lane & 31, half = lane >> 5;
    int xh = w >> 1, wh = w & 1;

    if (blockIdx.x < 32) {
        // ---- Q: 128 n x 128 co, Cin=128 ----
        int n0 = blockIdx.x * 128;
        const u16* xb = sr_t + (size_t)b * NN * C;
        f32x16 acc[2][2];
#pragma unroll
        for (int xt = 0; xt < 2; xt++)
#pragma unroll
            for (int wt2 = 0; wt2 < 2; wt2++)
#pragma unroll
                for (int i = 0; i < 16; i++) acc[xt][wt2][i] = 0.f;
        for (int c0i = 0; c0i < 2; c0i++) {
            int c0 = c0i * 64;
            __syncthreads();
#pragma unroll
            for (int t = 0; t < 4; t++) {
                int CI = t * 256 + tid;
                int row = CI >> 3, sl = CI & 7;
                int lc = sl ^ (row & 7);
                __builtin_amdgcn_global_load_lds(
                    (const __attribute__((address_space(1))) void*)(xb + (size_t)(n0 + row) * C + c0 + lc * 8),
                    (__attribute__((address_space(3))) void*)&xs[(size_t)CI * 8], 16, 0, 0);
            }
#pragma unroll
            for (int t = 0; t < 4; t++) {
                int CI = t * 256 + tid;
                int co = CI >> 3, sl = CI & 7;
                int lc = sl ^ (co & 7);
                __builtin_amdgcn_global_load_lds(
                    (const __attribute__((address_space(1))) void*)(wbf + (size_t)co * C + c0 + lc * 8),
                    (__attribute__((address_space(3))) void*)&wsm[0][(size_t)CI * 8], 16, 0, 0);
            }
            __syncthreads();
#pragma unroll
            for (int kg = 0; kg < 4; kg++) {
                int pc = ((kg * 2 + half) ^ (l31 & 7)) * 8;
                s16x8 xf[2], wf2[2];
#pragma unroll
                for (int xt = 0; xt < 2; xt++)
                    xf[xt] = *(const s16x8*)&xs[(xh * 64 + xt * 32 + l31) * 64 + pc];
#pragma unroll
                for (int wt2 = 0; wt2 < 2; wt2++)
                    wf2[wt2] = *(const s16x8*)&wsm[0][(wh * 64 + wt2 * 32 + l31) * 64 + pc];
#pragma unroll
                for (int xt = 0; xt < 2; xt++)
#pragma unroll
                    for (int wt2 = 0; wt2 < 2; wt2++)
                        acc[xt][wt2] = __builtin_amdgcn_mfma_f32_32x32x16_bf16(xf[xt], wf2[wt2], acc[xt][wt2], 0, 0, 0);
            }
        }
        u16* ot = q_t + (size_t)b * NN * C;
        float bv2[2];
#pragma unroll
        for (int wt2 = 0; wt2 < 2; wt2++) bv2[wt2] = bq[wh * 64 + wt2 * 32 + l31] * LOG2E;
#pragma unroll
        for (int xt = 0; xt < 2; xt++)
#pragma unroll
            for (int r = 0; r < 16; r++) {
                int n = n0 + xh * 64 + xt * 32 + (r & 3) + 8 * (r >> 2) + 4 * half;
#pragma unroll
                for (int wt2 = 0; wt2 < 2; wt2++)
                    ot[(size_t)n * C + wh * 64 + wt2 * 32 + l31] = f2bf(acc[xt][wt2][r] + bv2[wt2]);
            }
    } else {
        // ---- K & V: 64 source px x 128 co, Cin=256, ctx staged once ----
        int n0 = (blockIdx.x - 32) * 64;
        const u16* xb = ctx_s + (size_t)b * NS * CCH;
        const u16* wkb = wbf + 16384;
        const u16* wvb = wbf + 49152;
        f32x16 acck[2], accv[2];   // [wt2]; wave: n-tile xh*32, co wh*64+wt2*32
#pragma unroll
        for (int wt2 = 0; wt2 < 2; wt2++)
#pragma unroll
            for (int i = 0; i < 16; i++) { acck[wt2][i] = 0.f; accv[wt2][i] = 0.f; }
        for (int c0i = 0; c0i < 4; c0i++) {
            int c0 = c0i * 64;
            __syncthreads();
#pragma unroll
            for (int t = 0; t < 2; t++) {          // 64 rows x 8 chunks
                int CI = t * 256 + tid;
                int row = CI >> 3, sl = CI & 7;
                int lc = sl ^ (row & 7);
                __builtin_amdgcn_global_load_lds(
                    (const __attribute__((address_space(1))) void*)(xb + (size_t)(n0 + row) * CCH + c0 + lc * 8),
                    (__attribute__((address_space(3))) void*)&xs[(size_t)CI * 8], 16, 0, 0);
            }
#pragma unroll
            for (int t = 0; t < 4; t++) {
                int CI = t * 256 + tid;
                int co = CI >> 3, sl = CI & 7;
                int lc = sl ^ (co & 7);
                __builtin_amdgcn_global_load_lds(
                    (const __attribute__((address_space(1))) void*)(wkb + (size_t)co * CCH + c0 + lc * 8),
                    (__attribute__((address_space(3))) void*)&wsm[0][(size_t)CI * 8], 16, 0, 0);
            }
#pragma unroll
            for (int t = 0; t < 4; t++) {
                int CI = t * 256 + tid;
                int co = CI >> 3, sl = CI & 7;
                int lc = sl ^ (co & 7);
                __builtin_amdgcn_global_load_lds(
                    (const __attribute__((address_space(1))) void*)(wvb + (size_t)co * CCH + c0 + lc * 8),
                    (__attribute__((address_space(3))) void*)&wsm[1][(size_t)CI * 8], 16, 0, 0);
            }
            __syncthreads();
#pragma unroll
            for (int kg = 0; kg < 4; kg++) {
                int pc = ((kg * 2 + half) ^ (l31 & 7)) * 8;
                s16x8 xf = *(const s16x8*)&xs[(xh * 32 + l31) * 64 + pc];
                s16x8 wfk[2], wfv[2];
#pragma unroll
                for (int wt2 = 0; wt2 < 2; wt2++) {
                    wfk[wt2] = *(const s16x8*)&wsm[0][(wh * 64 + wt2 * 32 + l31) * 64 + pc];
                    wfv[wt2] = *(const s16x8*)&wsm[1][(wh * 64 + wt2 * 32 + l31) * 64 + pc];
                }
#pragma unroll
                for (int wt2 = 0; wt2 < 2; wt2++) {
                    acck[wt2] = __builtin_amdgcn_mfma_f32_32x32x16_bf16(xf, wfk[wt2], acck[wt2], 0, 0, 0);
                    accv[wt2] = __builtin_amdgcn_mfma_f32_32x32x16_bf16(wfv[wt2], xf, accv[wt2], 0, 0, 0);
                }
            }
        }
        // K epilogue: T-layout k_s[b][n][co]
        u16* ok = k_s + (size_t)b * NS * C;
#pragma unroll
        for (int wt2 = 0; wt2 < 2; wt2++) {
            float bvk = bk[wh * 64 + wt2 * 32 + l31];
#pragma unroll
            for (int r = 0; r < 16; r++) {
                int n = n0 + xh * 32 + (r & 3) + 8 * (r >> 2) + 4 * half;
                ok[(size_t)n * C + wh * 64 + wt2 * 32 + l31] = f2bf(acck[wt2][r] + bvk);
            }
        }
        // V epilogue: N-layout v_s[b][co][n]
        u16* ov = v_s + (size_t)b * C * NS;
#pragma unroll
        for (int wt2 = 0; wt2 < 2; wt2++)
#pragma unroll
            for (int r = 0; r < 16; r++) {
                int co = wh * 64 + wt2 * 32 + (r & 3) + 8 * (r >> 2) + 4 * half;
                ov[(size_t)co * NS + n0 + xh * 32 + l31] = f2bf(accv[wt2][r] + bv[co]);
            }
    }
}

// ---------------------------------------------------------------------------
// 3) upsample_v: v_s [b][C][1024] -> v [b][C][4096]
//    (bilinear, half-pixel centers, clamped — commutes with 1x1 conv)
// ---------------------------------------------------------------------------
__global__ __launch_bounds__(256) void upsample_v(const u16* __restrict__ v_s,
                                                  u16* __restrict__ v_bf) {
    __shared__ u16 lsv[NS];
    int idx = blockIdx.x;
    int tid = threadIdx.x;
    // one (b,c) plane: 1024 -> 4096
    int c = idx & 127, b = idx >> 7;
    const u16* vp = v_s + ((size_t)b * C + c) * NS;
    if (tid < 128) *(uint4*)&lsv[tid * 8] = *(const uint4*)(vp + tid * 8);
    __syncthreads();
    u16* ob = v_bf + ((size_t)b * C + c) * NN;
#pragma unroll
    for (int j = 0; j < 16; j++) {
        int n = tid + j * 256;
        int y = n >> 6, x = n & 63;
        float sy = y * 0.5f - 0.25f;
        float sx = x * 0.5f - 0.25f;
        int y0 = (int)floorf(sy), x0 = (int)floorf(sx);
        float wy = sy - (float)y0, wx = sx - (float)x0;
        int y0c = y0 < 0 ? 0 : y0;
        int y1c = (y0 + 1 > HC - 1) ? HC - 1 : y0 + 1;
        int x0c = x0 < 0 ? 0 : x0;
        int x1c = (x0 + 1 > WC - 1) ? WC - 1 : x0 + 1;
        float v00 = bf2f(lsv[y0c * WC + x0c]), v01 = bf2f(lsv[y0c * WC + x1c]);
        float v10 = bf2f(lsv[y1c * WC + x0c]), v11 = bf2f(lsv[y1c * WC + x1c]);
        ob[n] = f2bf((1.f - wy) * ((1.f - wx) * v00 + wx * v01)
                   +        wy  * ((1.f - wx) * v10 + wx * v11));
    }
}

// ---------------------------------------------------------------------------
// 4) Flash attention v11 (the champion, byte-identical):
//    score-space bilinear upsampling. Per split (16 fine rows), rolling
//    2-row window of SOURCE score tiles (32 src px x 32 q) in registers;
//    per y: y-lerp + x-stencil (0.25/0.75) + exp2 produces p directly in
//    the PV B-fragment layout; PV at fine res from double-buffered LDS V.
//    Score tiles computed one iteration ahead (sC) from 3 rotating 8KB
//    source-K row buffers so the 8-MFMA chain stays off the critical path.
// ---------------------------------------------------------------------------
__global__ __launch_bounds__(256, 2) void flash_mfma(const u16* __restrict__ qt_p,
                                                     const u16* __restrict__ ks_p,
                                                     const u16* __restrict__ vt_p,
                                                     u16* __restrict__ part,
                                                     float* __restrict__ lpart) {
    __shared__ u16 ksr[3][32 * 128];   // rotating source-K row buffers (8 KB each)
    __shared__ u16 vs[2][128 * 64];    // V double buffer (16 KB each)

    int ib = blockIdx.x;
    int b = (ib & 7) >> 1;
    int rest = ((ib >> 3) << 1) | (ib & 1);
    int qtile = rest >> 2;
    int split = rest & 3;
    int n0 = qtile * 128;
    int tid = threadIdx.x;
    int w = tid >> 6, lane = tid & 63, l31 = lane & 31, half = lane >> 5;

    const u16* qtb = qt_p + (size_t)b * NN * C;
    const u16* ksb = ks_p + (size_t)b * NS * C;
    const u16* vtb = vt_p + (size_t)b * C * NN;

    // stage source-K row r (32 px x 128 ch = 8 KB) into ksr[buf]
    auto stageKrow = [&](int buf, int r) {
#pragma unroll
        for (int t = 0; t < 2; t++) {
            int CI = t * 256 + tid;            // chunk 0..511
            int row = CI >> 4;                 // src px within row (jx)
            int lc = (CI & 15) ^ (row & 15);
            __builtin_amdgcn_global_load_lds(
                (const __attribute__((address_space(1))) void*)(ksb + (size_t)(r * 32 + row) * C + lc * 8),
                (__attribute__((address_space(3))) void*)&ksr[buf][(size_t)CI * 8], 16, 0, 0);
        }
    };
    auto stageV = [&](int buf, int m0) {
#pragma unroll
        for (int t = 0; t < 4; t++) {
            int CI = (w * 4 + t) * 64 + lane;
            int c = CI >> 3;
            int lc = (CI & 7) ^ (c & 7);
            __builtin_amdgcn_global_load_lds(
                (const __attribute__((address_space(1))) void*)(vtb + (size_t)c * NN + m0 + lc * 8),
                (__attribute__((address_space(3))) void*)&vs[buf][(w * 4 + t) * 512], 16, 0, 0);
        }
    };

    int qrow = n0 + w * 32 + l31;
    s16x8 qf[8];
#pragma unroll
    for (int kg = 0; kg < 8; kg++)
        qf[kg] = *(const s16x8*)(qtb + (size_t)qrow * C + kg * 16 + half * 8);

    // score tile: rows = 32 src px of one source row, cols = 32 q
    auto scoreTile = [&](int buf) {
        f32x16 st;
#pragma unroll
        for (int i = 0; i < 16; i++) st[i] = 0.f;
        const u16* kb = &ksr[buf][0];
#pragma unroll
        for (int kg = 0; kg < 8; kg++) {
            int pc = ((kg * 2 + half) ^ (l31 & 15)) * 8;
            s16x8 kf = *(const s16x8*)&kb[l31 * 128 + pc];
            st = __builtin_amdgcn_mfma_f32_32x32x16_bf16(kf, qf[kg], st, 0, 0, 0);
        }
        return st;
    };

    int m_base = split * 1024;
    int j0 = split * 8;   // first source row of this split's window

    // prologue: rows (j0-1 clamp, j0) for y=16*split, plus j0+1 for it=1
    stageKrow(0, split == 0 ? 0 : j0 - 1);
    stageKrow(1, j0);
    stageKrow(2, j0 + 1);              // j0+1 <= 25 always
    stageV(0, m_base);
    __syncthreads();
    f32x16 sA = scoreTile(0);          // score(rlo)
    f32x16 sB = scoreTile(1);          // score(rhi)
    f32x16 sC;                          // next row's tile (computed at even it)

    f32x16 oacc[4];
#pragma unroll
    for (int mt = 0; mt < 4; mt++)
#pragma unroll
        for (int i = 0; i < 16; i++) oacc[mt][i] = 0.f;
    float lsum = 0.f;

#pragma unroll 2
    for (int it = 0; it < 16; it++) {    // y = 16*split + it
        int buf = it & 1;
        int m0 = m_base + it * 64;
        if (it < 15) {
            stageV(buf ^ 1, m0 + 64);
            if (it & 1) {                         // stage row for compute at it+1
                int rs = j0 + 2 + (it >> 1);
                if (rs <= 31) stageKrow((it >> 1) % 3, rs);
            }
        }
        if (!(it & 1)) {                          // compute next tile ahead of use
            int rn = j0 + 1 + (it >> 1);
            if (rn <= 31) sC = scoreTile((2 + (it >> 1)) % 3);
        } else {                                  // window advance: rows (j, j+1)
            sA = sB;
            int rn = j0 + 1 + (it >> 1);
            if (rn <= 31) sB = sC;                // else clamp: keep row 31
        }

        // y-lerp: even y -> (0.25,0.75), odd y -> (0.75,0.25) on (rlo,rhi)
        float wB = (it & 1) ? 0.25f : 0.75f;
        float wA = 1.0f - wB;
        float cc[16];
#pragma unroll
        for (int i = 0; i < 16; i++) cc[i] = wA * sA[i] + wB * sB[i];

        // boundary exchange across lane-halves (rows interleave in blocks of 4)
        float xr0  = __shfl_xor(cc[0], 32);
        float xr3  = __shfl_xor(cc[3], 32);
        float xr4  = __shfl_xor(cc[4], 32);
        float xr7  = __shfl_xor(cc[7], 32);
        float xr8  = __shfl_xor(cc[8], 32);
        float xr11 = __shfl_xor(cc[11], 32);
        float xr12 = __shfl_xor(cc[12], 32);
        float xr15 = __shfl_xor(cc[15], 32);
        float d0s[4], d5s[4];
        d0s[0] = half ? xr3  : cc[0];   // x-block edge rows 4xb-1 (clamped at 0)
        d0s[1] = half ? xr7  : xr3;
        d0s[2] = half ? xr11 : xr7;
        d0s[3] = half ? xr15 : xr11;
        d5s[0] = half ? xr4  : xr0;     // rows 4xb+4 (clamped at 31)
        d5s[1] = half ? xr8  : xr4;
        d5s[2] = half ? xr12 : xr8;
        d5s[3] = half ? cc[15] : xr12;

        const u16* vsb = &vs[buf][0];
#pragma unroll
        for (int s = 0; s < 4; s++) {   // x-block xb = 2*s + half; x = 8*xb..+7
            float d0 = d0s[s], d1 = cc[4 * s], d2 = cc[4 * s + 1];
            float d3 = cc[4 * s + 2], d4 = cc[4 * s + 3], d5 = d5s[s];
            float e1 = 0.75f * d1, e2 = 0.75f * d2, e3 = 0.75f * d3, e4 = 0.75f * d4;
            float p0 = EXP2(fmaf(0.25f, d0, e1));
            float p1 = EXP2(fmaf(0.25f, d2, e1));
            float p2 = EXP2(fmaf(0.25f, d1, e2));
            float p3 = EXP2(fmaf(0.25f, d3, e2));
            float p4 = EXP2(fmaf(0.25f, d2, e3));
            float p5 = EXP2(fmaf(0.25f, d4, e3));
            float p6 = EXP2(fmaf(0.25f, d3, e4));
            float p7 = EXP2(fmaf(0.25f, d5, e4));
            lsum += ((p0 + p1) + (p2 + p3)) + ((p4 + p5) + (p6 + p7));
            union { uint32 u[4]; s16x8 v; } pu;
            pu.u[0] = __builtin_amdgcn_perm(__float_as_uint(p1), __float_as_uint(p0), 0x07060302u);
            pu.u[1] = __builtin_amdgcn_perm(__float_as_uint(p3), __float_as_uint(p2), 0x07060302u);
            pu.u[2] = __builtin_amdgcn_perm(__float_as_uint(p5), __float_as_uint(p4), 0x07060302u);
            pu.u[3] = __builtin_amdgcn_perm(__float_as_uint(p7), __float_as_uint(p6), 0x07060302u);
            int pcv = ((s * 2 + half) ^ (l31 & 7)) * 8;
#pragma unroll
            for (int mt = 0; mt < 4; mt++) {
                s16x8 vf = *(const s16x8*)&vsb[(mt * 32 + l31) * 64 + pcv];
                oacc[mt] = __builtin_amdgcn_mfma_f32_32x32x16_bf16(vf, pu.v, oacc[mt], 0, 0, 0);
            }
        }
        __syncthreads();
    }

    float lt = lsum + __shfl_xor(lsum, 32);
    if (half == 0) lpart[(size_t)split * NB * NN + (size_t)b * NN + qrow] = lt;
    u16* pb = part + ((size_t)split * NB + b) * (size_t)C * NN;
#pragma unroll
    for (int mt = 0; mt < 4; mt++)
#pragma unroll
        for (int r = 0; r < 16; r++) {
            int c = mt * 32 + (r & 3) + 8 * (r >> 2) + 4 * half;
            pb[(size_t)c * NN + n0 + w * 32 + l31] = f2bf(oacc[mt][r]);
        }
}

// ---------------------------------------------------------------------------
// 5) Combine, vectorized: part read as uint4 (8 bf16 along n, 16 loads/thread
//    vs 128 scalar), ts written as packed u32 (66-stride layout preserved so
//    phase-2 bank pattern is unchanged); phase-2 packs (c,c+1) pairs into u32
//    att_t stores. Math order & rounding identical to scalar version.
// ---------------------------------------------------------------------------
__global__ __launch_bounds__(256) void flash_combine(const u16* __restrict__ part,
                                                     const float* __restrict__ lpart,
                                                     u16* __restrict__ att_t) {
    __shared__ u16 ts[128 * 66];
    __shared__ float linv[64];
    int b = blockIdx.y;
    int nt = blockIdx.x;
    int n0 = nt * 64;
    int tid = threadIdx.x;
    if (tid < 64) {
        float s = 0.f;
#pragma unroll
        for (int sp = 0; sp < NSPLIT; sp++)
            s += lpart[(size_t)sp * NB * NN + (size_t)b * NN + n0 + tid];
        linv[tid] = 1.0f / s;
    }
    __syncthreads();
#pragma unroll
    for (int j = 0; j < 4; j++) {
        int idx = tid + j * 256;           // 0..1023: c = idx>>3, n-group = idx&7
        int c = idx >> 3, nb = idx & 7;
        float o[8];
#pragma unroll
        for (int t = 0; t < 8; t++) o[t] = 0.f;
#pragma unroll
        for (int sp = 0; sp < NSPLIT; sp++) {
            const u16* pp = part + ((size_t)sp * NB + b) * (size_t)C * NN
                          + (size_t)c * NN + n0 + nb * 8;
            uint4 v = *(const uint4*)pp;
            o[0] += __uint_as_float(v.x << 16);
            o[1] += __uint_as_float(v.x & 0xffff0000u);
            o[2] += __uint_as_float(v.y << 16);
            o[3] += __uint_as_float(v.y & 0xffff0000u);
            o[4] += __uint_as_float(v.z << 16);
            o[5] += __uint_as_float(v.z & 0xffff0000u);
            o[6] += __uint_as_float(v.w << 16);
            o[7] += __uint_as_float(v.w & 0xffff0000u);
        }
        u16* tp = &ts[c * 66 + nb * 8];    // 66c+8nb even -> 4B aligned
#pragma unroll
        for (int t = 0; t < 4; t++) {
            uint32 pk = (uint32)f2bf(o[2 * t] * linv[nb * 8 + 2 * t])
                      | ((uint32)f2bf(o[2 * t + 1] * linv[nb * 8 + 2 * t + 1]) << 16);
            *(uint32*)(tp + 2 * t) = pk;
        }
    }
    __syncthreads();
    u16* ob = att_t + ((size_t)b * PP * PP + (size_t)(nt + 1) * PP + 1) * C;
#pragma unroll
    for (int j = 0; j < 16; j++) {
        int o = tid + j * 256;             // 0..4095: (c-pair, n)
        int c2 = (o & 63) * 2, n = o >> 6;
        uint32 pk = (uint32)ts[c2 * 66 + n] | ((uint32)ts[(c2 + 1) * 66 + n] << 16);
        *(uint32*)&ob[(size_t)n * C + c2] = pk;
    }
}

// ---------------------------------------------------------------------------
// 6) Conv3x3 MFMA + residual (unchanged).
// ---------------------------------------------------------------------------
__global__ __launch_bounds__(256) void conv3x3_mfma(const u16* __restrict__ att_t,
                                                    const u16* __restrict__ wt,
                                                    const float* __restrict__ bp,
                                                    const float* __restrict__ sr,
                                                    const float* __restrict__ gamma,
                                                    float* __restrict__ out) {
    __shared__ u16 in_s[2][4 * 102 * 8];
    int ib = blockIdx.x;
    int b = (ib & 7) >> 1;
    int rr = ((ib >> 3) << 1) | (ib & 1);
    int y = rr >> 1;
    int x0 = (rr & 1) * 32;
    int tid = threadIdx.x;
    int w = tid >> 6, lane = tid & 63, l = tid & 15, quad = (tid >> 4) & 3;
    const u16* ab = att_t + (size_t)b * (PP * PP * C);

    auto stage = [&](int cib, int bufi) {
        u16* base = &in_s[bufi][w * 102 * 8];
        const u16* gsrc = ab + cib * 32 + w * 8;
#pragma unroll
        for (int t = 0; t < 2; t++) {
            int idx = t * 64 + lane;
            int r = idx / 34, xp = idx - r * 34;
            if (t == 0 || lane < 38)
                __builtin_amdgcn_global_load_lds(
                    (const __attribute__((address_space(1))) void*)(gsrc + (size_t)((y + r) * PP + x0 + xp) * C),
                    (__attribute__((address_space(3))) void*)(base + (size_t)t * 64 * 8), 16, 0, 0);
        }
    };

    f32x4 accr[2][2];
#pragma unroll
    for (int cf = 0; cf < 2; cf++)
#pragma unroll
        for (int nf = 0; nf < 2; nf++) accr[cf][nf] = (f32x4){0.f, 0.f, 0.f, 0.f};
    int cow = w * 32;

    stage(0, 0);
    __syncthreads();
#pragma unroll
    for (int cib = 0; cib < 4; cib++) {
        if (cib < 3) stage(cib + 1, (cib + 1) & 1);
        s16x8 wf[9][2];
#pragma unroll
        for (int pos = 0; pos < 9; pos++)
#pragma unroll
            for (int cf = 0; cf < 2; cf++)
                wf[pos][cf] = *(const s16x8*)&wt[((size_t)(pos * 4 + cib) * C + cow + cf * 16 + l) * 32 + quad * 8];
        const u16* bufc = &in_s[cib & 1][0];
#pragma unroll
        for (int ky = 0; ky < 3; ky++)
#pragma unroll
            for (int kx = 0; kx < 3; kx++) {
                int pos = ky * 3 + kx;
#pragma unroll
                for (int nf = 0; nf < 2; nf++) {
                    s16x8 inf = *(const s16x8*)&bufc[(quad * 102 + ky * 34 + nf * 16 + l + kx) * 8];
                    accr[0][nf] = __builtin_amdgcn_mfma_f32_16x16x32_bf16(wf[pos][0], inf, accr[0][nf], 0, 0, 0);
                    accr[1][nf] = __builtin_amdgcn_mfma_f32_16x16x32_bf16(wf[pos][1], inf, accr[1][nf], 0, 0, 0);
                }
            }
        __syncthreads();
    }

    float g = gamma[0];
    float* ob = out + (size_t)b * C * NN;
    const float* sb = sr + (size_t)b * C * NN;
#pragma unroll
    for (int cf = 0; cf < 2; cf++)
#pragma unroll
        for (int r = 0; r < 4; r++) {
            int co = cow + cf * 16 + quad * 4 + r;
            float bias = bp[co];
#pragma unroll
            for (int nf = 0; nf < 2; nf++) {
                size_t oo = (size_t)co * NN + y * 64 + x0 + nf * 16 + l;
                ob[oo] = sb[oo] + g * (accr[cf][nf][r] + bias);
            }
        }
}

// ---------------------------------------------------------------------------
extern "C" void kernel_launch(void* const* d_in, const int* in_sizes, int n_in,
                              void* d_out, int out_size, void* d_ws, size_t ws_size,
                              hipStream_t stream) {
    const float* sr    = (const float*)d_in[0];
    const float* ctx   = (const float*)d_in[1];
    const float* Wq    = (const float*)d_in[2];
    const float* bq    = (const float*)d_in[3];
    const float* Wk    = (const float*)d_in[4];
    const float* bk    = (const float*)d_in[5];
    const float* Wv    = (const float*)d_in[6];
    const float* bv    = (const float*)d_in[7];
    const float* Wp    = (const float*)d_in[8];
    const float* bp    = (const float*)d_in[9];
    const float* gamma = (const float*)d_in[10];
    float* out = (float*)d_out;

    // ws layout (MB): att_t@0 | part@5 (16MB) | lpart@21 | ctx_s@22 (2MB) |
    //   sr_t@25 (4MB) | q_t@29 (4MB) | k_s@33 (1MB) | v_s@34 (1MB) |
    //   v_bf@39 (4MB) | wt@43 | w_bf@43.5
    char* wsb = (char*)d_ws;
    u16*   att_t  = (u16*)wsb;
    u16*   part   = (u16*)(wsb + (5u << 20));
    float* lpart  = (float*)(wsb + (21u << 20));
    u16*   ctx_s  = (u16*)(wsb + (22u << 20));
    u16*   sr_t   = (u16*)(wsb + (25u << 20));
    u16*   q_t    = (u16*)(wsb + (29u << 20));
    u16*   k_s    = (u16*)(wsb + (33u << 20));
    u16*   v_s    = (u16*)(wsb + (34u << 20));
    u16*   v_bf   = (u16*)(wsb + (39u << 20));
    u16*   wt     = (u16*)(wsb + (43u << 20));
    u16*   w_bf   = (u16*)(wsb + (43u << 20) + (512u << 10));

    prep2<<<dim3(1729), 256, 0, stream>>>(ctx, sr, Wq, Wk, Wv, Wp,
                                          ctx_s, sr_t, w_bf, wt, (uint4*)att_t);
    proj_all2<<<dim3(48, NB), 256, 0, stream>>>(sr_t, ctx_s, w_bf, bq, bk, bv,
                                                q_t, k_s, v_s);
    upsample_v<<<dim3(512), 256, 0, stream>>>(v_s, v_bf);
    flash_mfma<<<dim3(512), 256, 0, stream>>>(q_t, k_s, v_bf, part, lpart);
    flash_combine<<<dim3(64, NB), 256, 0, stream>>>(part, lpart, att_t);
    conv3x3_mfma<<<dim3(512), 256, 0, stream>>>(att_t, wt, bp, sr, gamma, out);
}